// Round 5
// baseline (1069.245 us; speedup 1.0000x reference)
//
#include <hip/hip_runtime.h>
#include <hip/hip_bf16.h>

// Model dims: B=16, N=2048, F=40, D=256, H=8, K=256, L=4, DH=32
// fp32 inputs/outputs; bf16 MFMA for all GEMMs and attention, fp32 residual stream.

typedef short bf16x8 __attribute__((ext_vector_type(8)));
typedef float f32x4 __attribute__((ext_vector_type(4)));

#define GLOBAL_AS __attribute__((address_space(1)))
#define LDS_AS __attribute__((address_space(3)))

static __device__ __forceinline__ float gelu_f(float v) {
    return 0.5f * v * (1.0f + erff(v * 0.70710678118654752f));
}
static __device__ __forceinline__ ushort f2bf(float x) {
    __hip_bfloat16 h = __float2bfloat16(x);
    return __builtin_bit_cast(ushort, h);
}

// ---------------- embed + pos + LN0: wave-per-row, no syncthreads ----------------
__global__ __launch_bounds__(256)
void embed_ln2(const float* __restrict__ x, const float* __restrict__ Wemb,
               const float* __restrict__ bemb, const float* __restrict__ pos,
               const float* __restrict__ g0, const float* __restrict__ b0,
               float* __restrict__ H)
{
    const int t = threadIdx.x, w = t >> 6, l = t & 63;
    const long row = (long)blockIdx.x * 4 + w;
    const int n = (int)(row & 2047);
    const float xl = (l < 40) ? x[row * 40 + l] : 0.f;
    float4 acc = *(const float4*)&bemb[l * 4];
    const float4 pv = *(const float4*)&pos[(long)n * 256 + l * 4];
    acc.x += pv.x; acc.y += pv.y; acc.z += pv.z; acc.w += pv.w;
    #pragma unroll 8
    for (int f = 0; f < 40; ++f) {
        const float xf = __shfl(xl, f);
        const float4 wv = *(const float4*)&Wemb[f * 256 + l * 4];
        acc.x += xf * wv.x; acc.y += xf * wv.y; acc.z += xf * wv.z; acc.w += xf * wv.w;
    }
    float s = acc.x + acc.y + acc.z + acc.w;
    #pragma unroll
    for (int m = 32; m >= 1; m >>= 1) s += __shfl_xor(s, m);
    const float mean = s * (1.0f / 256.0f);
    const float dx = acc.x - mean, dy = acc.y - mean, dz = acc.z - mean, dw = acc.w - mean;
    float q = dx * dx + dy * dy + dz * dz + dw * dw;
    #pragma unroll
    for (int m = 32; m >= 1; m >>= 1) q += __shfl_xor(q, m);
    const float inv = rsqrtf(q * (1.0f / 256.0f) + 1e-5f);
    const float4 gv = *(const float4*)&g0[l * 4];
    const float4 bv = *(const float4*)&b0[l * 4];
    float4 y;
    y.x = dx * inv * gv.x + bv.x;
    y.y = dy * inv * gv.y + bv.y;
    y.z = dz * inv * gv.z + bv.z;
    y.w = dw * inv * gv.w + bv.w;
    *(float4*)&H[row * 256 + l * 4] = y;
}

// ---------------- LayerNorm fp32 -> bf16 ----------------
__global__ __launch_bounds__(256)
void ln_kernel(const float* __restrict__ X, const float* __restrict__ g,
               const float* __restrict__ b, ushort* __restrict__ Y)
{
    const int row = blockIdx.x * 4 + (threadIdx.x >> 6);
    const int lane = threadIdx.x & 63;
    const long base = (long)row * 256 + lane * 4;
    float4 xv = *(const float4*)&X[base];
    float s = xv.x + xv.y + xv.z + xv.w;
    #pragma unroll
    for (int m = 32; m >= 1; m >>= 1) s += __shfl_xor(s, m);
    const float mean = s * (1.0f / 256.0f);
    const float dx = xv.x - mean, dy = xv.y - mean, dz = xv.z - mean, dw = xv.w - mean;
    float q = dx * dx + dy * dy + dz * dz + dw * dw;
    #pragma unroll
    for (int m = 32; m >= 1; m >>= 1) q += __shfl_xor(q, m);
    const float inv = rsqrtf(q * (1.0f / 256.0f) + 1e-5f);
    const float4 gv = *(const float4*)&g[lane * 4];
    const float4 bv = *(const float4*)&b[lane * 4];
    ushort4 y;
    y.x = f2bf(dx * inv * gv.x + bv.x);
    y.y = f2bf(dy * inv * gv.y + bv.y);
    y.z = f2bf(dz * inv * gv.z + bv.z);
    y.w = f2bf(dw * inv * gv.w + bv.w);
    *(ushort4*)&Y[base] = y;
}

// ---------------- weight transpose + cast ----------------
__global__ __launch_bounds__(256)
void transpose_cast(const float* __restrict__ in, ushort* __restrict__ out,
                    int R, int C, long sIn, long sOut)
{
    __shared__ float tile[32][33];
    in += (long)blockIdx.z * sIn; out += (long)blockIdx.z * sOut;
    const int c0 = blockIdx.x * 32, r0 = blockIdx.y * 32;
    const int tx = threadIdx.x & 31, ty = threadIdx.x >> 5;
    #pragma unroll
    for (int j = 0; j < 4; ++j)
        tile[ty + j * 8][tx] = in[(long)(r0 + ty + j * 8) * C + c0 + tx];
    __syncthreads();
    #pragma unroll
    for (int j = 0; j < 4; ++j)
        out[(long)(c0 + ty + j * 8) * R + r0 + tx] = f2bf(tile[tx][ty + j * 8]);
}

// ---------------- activation transpose: abf [32768,256] -> aT [16][256][2048] ----------------
__global__ __launch_bounds__(256)
void transpose_act(const ushort* __restrict__ in, ushort* __restrict__ out)
{
    __shared__ ushort tile[32][33];
    const int c0 = blockIdx.x * 32, r0 = blockIdx.y * 32;
    const int tx = threadIdx.x & 31, ty = threadIdx.x >> 5;
    #pragma unroll
    for (int j = 0; j < 4; ++j)
        tile[ty + j * 8][tx] = in[(long)(r0 + ty + j * 8) * 256 + c0 + tx];
    __syncthreads();
    const int b = r0 >> 11, nn = r0 & 2047;
    #pragma unroll
    for (int j = 0; j < 4; ++j)
        out[((long)(b * 256 + c0 + ty + j * 8)) * 2048 + nn + tx] = tile[tx][ty + j * 8];
}

// ---------------- bf16 MFMA GEMM, m97 structure ----------------
// C[bz] = op( A[bz] @ BT[bz]^T ) — A [M,Kd] bf16, BT [N,Kd] bf16 (pre-transposed B).
// MT=128: 128x128 tile, 4 waves in 2x2, each 64x64 (4x4 frags).
// MT=64 :  64x128 tile, 4 waves side by side, each 64x32 (4x2 frags).
template<int OBF16, int ACCUM, int ACT, int HASB, int MT>
__global__ __launch_bounds__(256)
void gemm_bf16(const ushort* __restrict__ A, const ushort* __restrict__ BT,
               const float* __restrict__ bias, void* __restrict__ Cout,
               int Kd, int lda, int ldb, int ldc,
               long sA, long sBT, long sC)
{
    constexpr int NF  = (MT == 128) ? 4 : 2;    // col frags per wave
    constexpr int CPW = (MT == 128) ? 64 : 32;  // cols per wave
    __shared__ ushort Als[MT * 32];
    __shared__ ushort Bls[128 * 32];
    const int bz = blockIdx.z;
    const ushort* Ab = A + (long)bz * sA;
    const ushort* Bb = BT + (long)bz * sBT;
    const int m0 = blockIdx.x * MT, n0 = blockIdx.y * 128;
    const int t = threadIdx.x, l = t & 63, w = t >> 6;
    const int wr = (MT == 128) ? (w >> 1) : 0;
    const int wc = (MT == 128) ? (w & 1) : w;
    const int fr = l & 15, fq = l >> 4;

    f32x4 acc[4][NF];
    #pragma unroll
    for (int m = 0; m < 4; ++m)
        #pragma unroll
        for (int n = 0; n < NF; ++n) acc[m][n] = f32x4{0.f, 0.f, 0.f, 0.f};

    const int srow = t >> 2;
    const int skcol = (t & 3) * 8;
    const int dst0 = w * 512;

    for (int kk = 0; kk < Kd; kk += 32) {
        const ushort* ag = Ab + (long)(m0 + srow) * lda + kk + skcol;
        const ushort* bg = Bb + (long)(n0 + srow) * ldb + kk + skcol;
        __builtin_amdgcn_global_load_lds((const GLOBAL_AS void*)ag,
                                         (LDS_AS void*)&Als[dst0], 16, 0, 0);
        if (MT == 128)
            __builtin_amdgcn_global_load_lds((const GLOBAL_AS void*)(ag + (long)64 * lda),
                                             (LDS_AS void*)&Als[2048 + dst0], 16, 0, 0);
        __builtin_amdgcn_global_load_lds((const GLOBAL_AS void*)bg,
                                         (LDS_AS void*)&Bls[dst0], 16, 0, 0);
        __builtin_amdgcn_global_load_lds((const GLOBAL_AS void*)(bg + (long)64 * ldb),
                                         (LDS_AS void*)&Bls[2048 + dst0], 16, 0, 0);
        __syncthreads();
        bf16x8 af[4], bfv[NF];
        #pragma unroll
        for (int m = 0; m < 4; ++m)
            af[m] = *(const bf16x8*)&Als[(wr * 64 + m * 16 + fr) * 32 + fq * 8];
        #pragma unroll
        for (int n = 0; n < NF; ++n)
            bfv[n] = *(const bf16x8*)&Bls[(wc * CPW + n * 16 + fr) * 32 + fq * 8];
        #pragma unroll
        for (int m = 0; m < 4; ++m)
            #pragma unroll
            for (int n = 0; n < NF; ++n)
                acc[m][n] = __builtin_amdgcn_mfma_f32_16x16x32_bf16(af[m], bfv[n], acc[m][n], 0, 0, 0);
        __syncthreads();
    }

    float bsv[NF];
    #pragma unroll
    for (int n = 0; n < NF; ++n) bsv[n] = HASB ? bias[n0 + wc * CPW + n * 16 + fr] : 0.f;
    #pragma unroll
    for (int m = 0; m < 4; ++m) {
        #pragma unroll
        for (int r = 0; r < 4; ++r) {
            const int grow = m0 + wr * 64 + m * 16 + fq * 4 + r;
            const long rowoff = (long)grow * ldc + n0 + wc * CPW + fr;
            #pragma unroll
            for (int n = 0; n < NF; ++n) {
                float v = acc[m][n][r] + bsv[n];
                if (ACT) v = gelu_f(v);
                const long off = rowoff + n * 16;
                if (OBF16) {
                    ((ushort*)Cout)[(long)bz * sC + off] = f2bf(v);
                } else {
                    float* Cp = (float*)Cout + (long)bz * sC;
                    if (ACCUM) v += Cp[off];
                    Cp[off] = v;
                }
            }
        }
    }
}

// ---------------- fused MFMA attention ----------------
__global__ __launch_bounds__(256)
void attn_mfma(const ushort* __restrict__ Q, const ushort* __restrict__ Kp,
               const ushort* __restrict__ VpT, ushort* __restrict__ O)
{
    __shared__ ushort Qls[64 * 40];
    __shared__ ushort Kls[256 * 40];
    __shared__ ushort Vls[32 * 264];
    __shared__ ushort Pls[64 * 264];
    const int qt = blockIdx.x, h = blockIdx.y, b = blockIdx.z;
    const int n0 = qt * 64;
    const int t = threadIdx.x, w = t >> 6, l = t & 63;
    const int fr = l & 15, fq = l >> 4;

    {
        const int r = t >> 2, c = (t & 3) * 8;
        *(float4*)&Qls[r * 40 + c] =
            *(const float4*)&Q[((long)(b * 2048 + n0 + r)) * 256 + h * 32 + c];
    }
    #pragma unroll
    for (int it = 0; it < 4; ++it) {
        const int r = (t >> 2) + it * 64, c = (t & 3) * 8;
        *(float4*)&Kls[r * 40 + c] =
            *(const float4*)&Kp[((long)(b * 256 + r)) * 256 + h * 32 + c];
    }
    {
        const int r = t >> 3, c0 = (t & 7) * 32;
        const ushort* src = VpT + ((long)(b * 256 + h * 32 + r)) * 256 + c0;
        #pragma unroll
        for (int j = 0; j < 4; ++j)
            *(float4*)&Vls[r * 264 + c0 + j * 8] = *(const float4*)(src + j * 8);
    }
    __syncthreads();

    const bf16x8 aq = *(const bf16x8*)&Qls[(w * 16 + fr) * 40 + fq * 8];
    f32x4 s[16];
    #pragma unroll
    for (int n = 0; n < 16; ++n) {
        const bf16x8 bk = *(const bf16x8*)&Kls[(n * 16 + fr) * 40 + fq * 8];
        s[n] = __builtin_amdgcn_mfma_f32_16x16x32_bf16(aq, bk, f32x4{0.f,0.f,0.f,0.f}, 0, 0, 0);
    }
    const float scale = 0.17677669529663687f;
    float mx[4] = {-1e30f, -1e30f, -1e30f, -1e30f};
    #pragma unroll
    for (int n = 0; n < 16; ++n)
        #pragma unroll
        for (int r = 0; r < 4; ++r) { s[n][r] *= scale; mx[r] = fmaxf(mx[r], s[n][r]); }
    #pragma unroll
    for (int m = 1; m <= 8; m <<= 1)
        #pragma unroll
        for (int r = 0; r < 4; ++r) mx[r] = fmaxf(mx[r], __shfl_xor(mx[r], m));
    float sm[4] = {0.f, 0.f, 0.f, 0.f};
    #pragma unroll
    for (int n = 0; n < 16; ++n)
        #pragma unroll
        for (int r = 0; r < 4; ++r) {
            const float e = __expf(s[n][r] - mx[r]);
            s[n][r] = e; sm[r] += e;
        }
    #pragma unroll
    for (int m = 1; m <= 8; m <<= 1)
        #pragma unroll
        for (int r = 0; r < 4; ++r) sm[r] += __shfl_xor(sm[r], m);
    #pragma unroll
    for (int n = 0; n < 16; ++n)
        #pragma unroll
        for (int r = 0; r < 4; ++r)
            Pls[(w * 16 + fq * 4 + r) * 264 + n * 16 + fr] = f2bf(s[n][r]);
    __syncthreads();

    f32x4 o[2] = {f32x4{0.f,0.f,0.f,0.f}, f32x4{0.f,0.f,0.f,0.f}};
    #pragma unroll
    for (int kk = 0; kk < 8; ++kk) {
        const bf16x8 ap = *(const bf16x8*)&Pls[(w * 16 + fr) * 264 + kk * 32 + fq * 8];
        #pragma unroll
        for (int n = 0; n < 2; ++n) {
            const bf16x8 bv = *(const bf16x8*)&Vls[(n * 16 + fr) * 264 + kk * 32 + fq * 8];
            o[n] = __builtin_amdgcn_mfma_f32_16x16x32_bf16(ap, bv, o[n], 0, 0, 0);
        }
    }
    float inv[4];
    #pragma unroll
    for (int r = 0; r < 4; ++r) inv[r] = 1.0f / sm[r];
    #pragma unroll
    for (int n = 0; n < 2; ++n)
        #pragma unroll
        for (int r = 0; r < 4; ++r)
            O[((long)(b * 2048 + n0 + w * 16 + fq * 4 + r)) * 256 + h * 32 + n * 16 + fr] =
                f2bf(o[n][r] * inv[r]);
}

// ---------------- final head ----------------
__global__ __launch_bounds__(256)
void out_kernel(const float* __restrict__ H, const float* __restrict__ Wout,
                const float* __restrict__ bout, float* __restrict__ out)
{
    const int row = blockIdx.x * 4 + (threadIdx.x >> 6);
    const int lane = threadIdx.x & 63;
    float4 hv = *(const float4*)&H[(long)row * 256 + lane * 4];
    float4 wv = *(const float4*)&Wout[lane * 4];
    float s = hv.x * wv.x + hv.y * wv.y + hv.z * wv.z + hv.w * wv.w;
    #pragma unroll
    for (int m = 32; m >= 1; m >>= 1) s += __shfl_xor(s, m);
    if (lane == 0) out[row] = s + bout[0];
}

extern "C" void kernel_launch(void* const* d_in, const int* in_sizes, int n_in,
                              void* d_out, int out_size, void* d_ws, size_t ws_size,
                              hipStream_t stream)
{
    const float* x    = (const float*)d_in[0];
    const float* Wemb = (const float*)d_in[1];
    const float* bemb = (const float*)d_in[2];
    const float* pos  = (const float*)d_in[3];
    const float* ln0g = (const float*)d_in[4];
    const float* ln0b = (const float*)d_in[5];
    const float* ln1g = (const float*)d_in[6];
    const float* ln1b = (const float*)d_in[7];
    const float* Wq   = (const float*)d_in[8];
    const float* Wk   = (const float*)d_in[9];
    const float* Wv   = (const float*)d_in[10];
    const float* Ek   = (const float*)d_in[11];
    const float* Ev   = (const float*)d_in[12];
    const float* Wo   = (const float*)d_in[13];
    const float* bo   = (const float*)d_in[14];
    const float* ln2g = (const float*)d_in[15];
    const float* ln2b = (const float*)d_in[16];
    const float* W1   = (const float*)d_in[17];
    const float* b1   = (const float*)d_in[18];
    const float* W2   = (const float*)d_in[19];
    const float* b2   = (const float*)d_in[20];
    const float* Wout = (const float*)d_in[21];
    const float* bout = (const float*)d_in[22];

    char* ws = (char*)d_ws;
    float*  h    = (float*)(ws + 0);                    // 33.5 MB
    ushort* abf  = (ushort*)(ws + 33554432L);           // 16.8 MB  [32768,256] bf16
    ushort* aT   = (ushort*)(ws + 50331648L);           // 16.8 MB  [16][256][2048] bf16
    ushort* qbf  = (ushort*)(ws + 67108864L);           // 33.5 MB  q bf16 [32768,256] / FFN hidden [32768,512]
    ushort* apkv = (ushort*)(ws + 100663296L);          //  4.2 MB  [16][512][256] bf16
    ushort* kp   = (ushort*)(ws + 104857600L);          //  2.1 MB  [16][256][256] bf16 (row=key)
    ushort* vpT  = (ushort*)(ws + 109051904L);          //  2.1 MB  [16][256][256] bf16 (row=d)
    ushort* WT   = (ushort*)(ws + 113246208L);          // 14.7 MB
    ushort* WqT  = WT;
    ushort* WkT  = WT + 262144;
    ushort* WvT  = WT + 524288;
    ushort* WoT  = WT + 786432;
    ushort* W1T  = WT + 1048576;
    ushort* W2T  = WT + 2097152;
    ushort* EkvT = WT + 3145728;
    float* outp = (float*)d_out;

    transpose_cast<<<dim3(8, 8, 4), 256, 0, stream>>>(Wq, WqT, 256, 256, 65536, 65536);
    transpose_cast<<<dim3(8, 8, 4), 256, 0, stream>>>(Wk, WkT, 256, 256, 65536, 65536);
    transpose_cast<<<dim3(8, 8, 4), 256, 0, stream>>>(Wv, WvT, 256, 256, 65536, 65536);
    transpose_cast<<<dim3(8, 8, 4), 256, 0, stream>>>(Wo, WoT, 256, 256, 65536, 65536);
    transpose_cast<<<dim3(32, 8, 4), 256, 0, stream>>>(W1, W1T, 256, 1024, 262144, 262144);
    transpose_cast<<<dim3(8, 32, 4), 256, 0, stream>>>(W2, W2T, 1024, 256, 262144, 262144);
    transpose_cast<<<dim3(8, 64, 4), 256, 0, stream>>>(Ek, EkvT, 2048, 256, 524288, 1048576);
    transpose_cast<<<dim3(8, 64, 4), 256, 0, stream>>>(Ev, EkvT + 524288, 2048, 256, 524288, 1048576);

    embed_ln2<<<8192, 256, 0, stream>>>(x, Wemb, bemb, pos, ln0g, ln0b, h);

    for (int i = 0; i < 4; ++i) {
        const ushort* WqT_i = WqT + i * 65536;
        const ushort* WkT_i = WkT + i * 65536;
        const ushort* WvT_i = WvT + i * 65536;
        const ushort* WoT_i = WoT + i * 65536;
        const ushort* W1T_i = W1T + i * 262144;
        const ushort* W2T_i = W2T + i * 262144;
        const ushort* EkvT_i = EkvT + (long)i * 1048576;

        // a = LN1(h) -> bf16 ; aT = transpose(a)
        ln_kernel<<<8192, 256, 0, stream>>>(h, ln1g + i * 256, ln1b + i * 256, abf);
        transpose_act<<<dim3(8, 1024), 256, 0, stream>>>(abf, aT);
        // q = a @ Wq  (bf16 out)
        gemm_bf16<1,0,0,0,128><<<dim3(256, 2, 1), 256, 0, stream>>>(abf, WqT_i, nullptr, qbf,
            256, 256, 256, 256, 0, 0, 0);
        // apkv[b] = [Ek^T; Ev^T] @ a[b]  (bf16 out) — 64-row tiles, 256 blocks
        gemm_bf16<1,0,0,0,64><<<dim3(8, 2, 16), 256, 0, stream>>>(EkvT_i, aT, nullptr, apkv,
            2048, 2048, 2048, 256, 0, 524288, 131072);
        // kp[b] = apk[b] @ Wk (bf16, row=key)
        gemm_bf16<1,0,0,0,64><<<dim3(4, 2, 16), 256, 0, stream>>>(apkv, WkT_i, nullptr, kp,
            256, 256, 256, 256, 131072, 0, 65536);
        // vpT[b] = Wv^T @ apv[b]^T  (bf16, row=d, col=key)
        gemm_bf16<1,0,0,0,64><<<dim3(4, 2, 16), 256, 0, stream>>>(WvT_i, apkv + 65536, nullptr, vpT,
            256, 256, 256, 256, 0, 131072, 65536);
        // fused MFMA attention -> abf (bf16)
        attn_mfma<<<dim3(32, 8, 16), 256, 0, stream>>>(qbf, kp, vpT, abf);
        // h += attnout @ Wo + bo
        gemm_bf16<0,1,0,1,128><<<dim3(256, 2, 1), 256, 0, stream>>>(abf, WoT_i, bo + i * 256, h,
            256, 256, 256, 256, 0, 0, 0);
        // a = LN2(h)
        ln_kernel<<<8192, 256, 0, stream>>>(h, ln2g + i * 256, ln2b + i * 256, abf);
        // FFN, 2 hidden chunks of 512 (m97 GEMMs, gelu fused in g1, f32 accum in g2)
        for (int c = 0; c < 2; ++c) {
            gemm_bf16<1,0,1,1,128><<<dim3(256, 4, 1), 256, 0, stream>>>(abf, W1T_i + c * 131072,
                b1 + (long)i * 1024 + c * 512, qbf,
                256, 256, 256, 512, 0, 0, 0);
            if (c == 0)
                gemm_bf16<0,1,0,1,128><<<dim3(256, 2, 1), 256, 0, stream>>>(qbf,
                    W2T_i + c * 512, b2 + i * 256, h, 512, 512, 1024, 256, 0, 0, 0);
            else
                gemm_bf16<0,1,0,0,128><<<dim3(256, 2, 1), 256, 0, stream>>>(qbf,
                    W2T_i + c * 512, nullptr, h, 512, 512, 1024, 256, 0, 0, 0);
        }
    }
    out_kernel<<<8192, 256, 0, stream>>>(h, Wout, bout, outp);
}

// Round 6
// 1009.733 us; speedup vs baseline: 1.0589x; 1.0589x over previous
//
#include <hip/hip_runtime.h>
#include <hip/hip_bf16.h>

// Model dims: B=16, N=2048, F=40, D=256, H=8, K=256, L=4, DH=32
// fp32 inputs/outputs; bf16 MFMA for all GEMMs and attention, fp32 residual stream.

typedef short bf16x8 __attribute__((ext_vector_type(8)));
typedef float f32x4 __attribute__((ext_vector_type(4)));

#define GLOBAL_AS __attribute__((address_space(1)))
#define LDS_AS __attribute__((address_space(3)))

static __device__ __forceinline__ float gelu_f(float v) {
    return 0.5f * v * (1.0f + erff(v * 0.70710678118654752f));
}
static __device__ __forceinline__ ushort f2bf(float x) {
    __hip_bfloat16 h = __float2bfloat16(x);
    return __builtin_bit_cast(ushort, h);
}

// ---------------- embed + pos + LN0: wave-per-row, no syncthreads ----------------
__global__ __launch_bounds__(256)
void embed_ln2(const float* __restrict__ x, const float* __restrict__ Wemb,
               const float* __restrict__ bemb, const float* __restrict__ pos,
               const float* __restrict__ g0, const float* __restrict__ b0,
               float* __restrict__ H)
{
    const int t = threadIdx.x, w = t >> 6, l = t & 63;
    const long row = (long)blockIdx.x * 4 + w;
    const int n = (int)(row & 2047);
    const float xl = (l < 40) ? x[row * 40 + l] : 0.f;
    float4 acc = *(const float4*)&bemb[l * 4];
    const float4 pv = *(const float4*)&pos[(long)n * 256 + l * 4];
    acc.x += pv.x; acc.y += pv.y; acc.z += pv.z; acc.w += pv.w;
    #pragma unroll 8
    for (int f = 0; f < 40; ++f) {
        const float xf = __shfl(xl, f);
        const float4 wv = *(const float4*)&Wemb[f * 256 + l * 4];
        acc.x += xf * wv.x; acc.y += xf * wv.y; acc.z += xf * wv.z; acc.w += xf * wv.w;
    }
    float s = acc.x + acc.y + acc.z + acc.w;
    #pragma unroll
    for (int m = 32; m >= 1; m >>= 1) s += __shfl_xor(s, m);
    const float mean = s * (1.0f / 256.0f);
    const float dx = acc.x - mean, dy = acc.y - mean, dz = acc.z - mean, dw = acc.w - mean;
    float q = dx * dx + dy * dy + dz * dz + dw * dw;
    #pragma unroll
    for (int m = 32; m >= 1; m >>= 1) q += __shfl_xor(q, m);
    const float inv = rsqrtf(q * (1.0f / 256.0f) + 1e-5f);
    const float4 gv = *(const float4*)&g0[l * 4];
    const float4 bv = *(const float4*)&b0[l * 4];
    float4 y;
    y.x = dx * inv * gv.x + bv.x;
    y.y = dy * inv * gv.y + bv.y;
    y.z = dz * inv * gv.z + bv.z;
    y.w = dw * inv * gv.w + bv.w;
    *(float4*)&H[row * 256 + l * 4] = y;
}

// ---------------- LayerNorm fp32 -> bf16 ----------------
__global__ __launch_bounds__(256)
void ln_kernel(const float* __restrict__ X, const float* __restrict__ g,
               const float* __restrict__ b, ushort* __restrict__ Y)
{
    const int row = blockIdx.x * 4 + (threadIdx.x >> 6);
    const int lane = threadIdx.x & 63;
    const long base = (long)row * 256 + lane * 4;
    float4 xv = *(const float4*)&X[base];
    float s = xv.x + xv.y + xv.z + xv.w;
    #pragma unroll
    for (int m = 32; m >= 1; m >>= 1) s += __shfl_xor(s, m);
    const float mean = s * (1.0f / 256.0f);
    const float dx = xv.x - mean, dy = xv.y - mean, dz = xv.z - mean, dw = xv.w - mean;
    float q = dx * dx + dy * dy + dz * dz + dw * dw;
    #pragma unroll
    for (int m = 32; m >= 1; m >>= 1) q += __shfl_xor(q, m);
    const float inv = rsqrtf(q * (1.0f / 256.0f) + 1e-5f);
    const float4 gv = *(const float4*)&g[lane * 4];
    const float4 bv = *(const float4*)&b[lane * 4];
    ushort4 y;
    y.x = f2bf(dx * inv * gv.x + bv.x);
    y.y = f2bf(dy * inv * gv.y + bv.y);
    y.z = f2bf(dz * inv * gv.z + bv.z);
    y.w = f2bf(dw * inv * gv.w + bv.w);
    *(ushort4*)&Y[base] = y;
}

// ---------------- weight transpose + cast ----------------
__global__ __launch_bounds__(256)
void transpose_cast(const float* __restrict__ in, ushort* __restrict__ out,
                    int R, int C, long sIn, long sOut)
{
    __shared__ float tile[32][33];
    in += (long)blockIdx.z * sIn; out += (long)blockIdx.z * sOut;
    const int c0 = blockIdx.x * 32, r0 = blockIdx.y * 32;
    const int tx = threadIdx.x & 31, ty = threadIdx.x >> 5;
    #pragma unroll
    for (int j = 0; j < 4; ++j)
        tile[ty + j * 8][tx] = in[(long)(r0 + ty + j * 8) * C + c0 + tx];
    __syncthreads();
    #pragma unroll
    for (int j = 0; j < 4; ++j)
        out[(long)(c0 + ty + j * 8) * R + r0 + tx] = f2bf(tile[tx][ty + j * 8]);
}

// ---------------- activation transpose: abf [32768,256] -> aT [16][256][2048] ----------------
__global__ __launch_bounds__(256)
void transpose_act(const ushort* __restrict__ in, ushort* __restrict__ out)
{
    __shared__ ushort tile[32][33];
    const int c0 = blockIdx.x * 32, r0 = blockIdx.y * 32;
    const int tx = threadIdx.x & 31, ty = threadIdx.x >> 5;
    #pragma unroll
    for (int j = 0; j < 4; ++j)
        tile[ty + j * 8][tx] = in[(long)(r0 + ty + j * 8) * 256 + c0 + tx];
    __syncthreads();
    const int b = r0 >> 11, nn = r0 & 2047;
    #pragma unroll
    for (int j = 0; j < 4; ++j)
        out[((long)(b * 256 + c0 + ty + j * 8)) * 2048 + nn + tx] = tile[tx][ty + j * 8];
}

// ---------------- bf16 MFMA GEMM, m97 structure ----------------
// C[bz] = op( A[bz] @ BT[bz]^T ) — A [M,Kd] bf16, BT [N,Kd] bf16 (pre-transposed B).
// MT=128: 128x128 tile, 4 waves in 2x2, each 64x64 (4x4 frags).
// MT=64 :  64x128 tile, 4 waves side by side, each 64x32 (4x2 frags).
// DUALA=1: A supplies k < kSplit, A2 supplies k >= kSplit (same lda, no batch offset on A2).
template<int OBF16, int ACCUM, int ACT, int HASB, int MT, int DUALA>
__global__ __launch_bounds__(256)
void gemm_bf16(const ushort* __restrict__ A, const ushort* __restrict__ BT,
               const float* __restrict__ bias, void* __restrict__ Cout,
               int Kd, int lda, int ldb, int ldc,
               long sA, long sBT, long sC,
               const ushort* __restrict__ A2, int kSplit)
{
    constexpr int NF  = (MT == 128) ? 4 : 2;    // col frags per wave
    constexpr int CPW = (MT == 128) ? 64 : 32;  // cols per wave
    __shared__ ushort Als[MT * 32];
    __shared__ ushort Bls[128 * 32];
    const int bz = blockIdx.z;
    const ushort* Ab = A + (long)bz * sA;
    const ushort* Bb = BT + (long)bz * sBT;
    const int m0 = blockIdx.x * MT, n0 = blockIdx.y * 128;
    const int t = threadIdx.x, l = t & 63, w = t >> 6;
    const int wr = (MT == 128) ? (w >> 1) : 0;
    const int wc = (MT == 128) ? (w & 1) : w;
    const int fr = l & 15, fq = l >> 4;

    f32x4 acc[4][NF];
    #pragma unroll
    for (int m = 0; m < 4; ++m)
        #pragma unroll
        for (int n = 0; n < NF; ++n) acc[m][n] = f32x4{0.f, 0.f, 0.f, 0.f};

    const int srow = t >> 2;
    const int skcol = (t & 3) * 8;
    const int dst0 = w * 512;

    for (int kk = 0; kk < Kd; kk += 32) {
        const ushort* ag;
        if (DUALA && kk >= kSplit)
            ag = A2 + (long)(m0 + srow) * lda + (kk - kSplit) + skcol;
        else
            ag = Ab + (long)(m0 + srow) * lda + kk + skcol;
        const ushort* bg = Bb + (long)(n0 + srow) * ldb + kk + skcol;
        __builtin_amdgcn_global_load_lds((const GLOBAL_AS void*)ag,
                                         (LDS_AS void*)&Als[dst0], 16, 0, 0);
        if (MT == 128)
            __builtin_amdgcn_global_load_lds((const GLOBAL_AS void*)(ag + (long)64 * lda),
                                             (LDS_AS void*)&Als[2048 + dst0], 16, 0, 0);
        __builtin_amdgcn_global_load_lds((const GLOBAL_AS void*)bg,
                                         (LDS_AS void*)&Bls[dst0], 16, 0, 0);
        __builtin_amdgcn_global_load_lds((const GLOBAL_AS void*)(bg + (long)64 * ldb),
                                         (LDS_AS void*)&Bls[2048 + dst0], 16, 0, 0);
        __syncthreads();
        bf16x8 af[4], bfv[NF];
        #pragma unroll
        for (int m = 0; m < 4; ++m)
            af[m] = *(const bf16x8*)&Als[(wr * 64 + m * 16 + fr) * 32 + fq * 8];
        #pragma unroll
        for (int n = 0; n < NF; ++n)
            bfv[n] = *(const bf16x8*)&Bls[(wc * CPW + n * 16 + fr) * 32 + fq * 8];
        #pragma unroll
        for (int m = 0; m < 4; ++m)
            #pragma unroll
            for (int n = 0; n < NF; ++n)
                acc[m][n] = __builtin_amdgcn_mfma_f32_16x16x32_bf16(af[m], bfv[n], acc[m][n], 0, 0, 0);
        __syncthreads();
    }

    float bsv[NF];
    #pragma unroll
    for (int n = 0; n < NF; ++n) bsv[n] = HASB ? bias[n0 + wc * CPW + n * 16 + fr] : 0.f;
    #pragma unroll
    for (int m = 0; m < 4; ++m) {
        #pragma unroll
        for (int r = 0; r < 4; ++r) {
            const int grow = m0 + wr * 64 + m * 16 + fq * 4 + r;
            const long rowoff = (long)grow * ldc + n0 + wc * CPW + fr;
            #pragma unroll
            for (int n = 0; n < NF; ++n) {
                float v = acc[m][n][r] + bsv[n];
                if (ACT) v = gelu_f(v);
                const long off = rowoff + n * 16;
                if (OBF16) {
                    ((ushort*)Cout)[(long)bz * sC + off] = f2bf(v);
                } else {
                    float* Cp = (float*)Cout + (long)bz * sC;
                    if (ACCUM) v += Cp[off];
                    Cp[off] = v;
                }
            }
        }
    }
}

// ---------------- fused MFMA attention ----------------
__global__ __launch_bounds__(256)
void attn_mfma(const ushort* __restrict__ Q, const ushort* __restrict__ Kp,
               const ushort* __restrict__ VpT, ushort* __restrict__ O)
{
    __shared__ ushort Qls[64 * 40];
    __shared__ ushort Kls[256 * 40];
    __shared__ ushort Vls[32 * 264];
    __shared__ ushort Pls[64 * 264];
    const int qt = blockIdx.x, h = blockIdx.y, b = blockIdx.z;
    const int n0 = qt * 64;
    const int t = threadIdx.x, w = t >> 6, l = t & 63;
    const int fr = l & 15, fq = l >> 4;

    {
        const int r = t >> 2, c = (t & 3) * 8;
        *(float4*)&Qls[r * 40 + c] =
            *(const float4*)&Q[((long)(b * 2048 + n0 + r)) * 256 + h * 32 + c];
    }
    #pragma unroll
    for (int it = 0; it < 4; ++it) {
        const int r = (t >> 2) + it * 64, c = (t & 3) * 8;
        *(float4*)&Kls[r * 40 + c] =
            *(const float4*)&Kp[((long)(b * 256 + r)) * 256 + h * 32 + c];
    }
    {
        const int r = t >> 3, c0 = (t & 7) * 32;
        const ushort* src = VpT + ((long)(b * 256 + h * 32 + r)) * 256 + c0;
        #pragma unroll
        for (int j = 0; j < 4; ++j)
            *(float4*)&Vls[r * 264 + c0 + j * 8] = *(const float4*)(src + j * 8);
    }
    __syncthreads();

    const bf16x8 aq = *(const bf16x8*)&Qls[(w * 16 + fr) * 40 + fq * 8];
    f32x4 s[16];
    #pragma unroll
    for (int n = 0; n < 16; ++n) {
        const bf16x8 bk = *(const bf16x8*)&Kls[(n * 16 + fr) * 40 + fq * 8];
        s[n] = __builtin_amdgcn_mfma_f32_16x16x32_bf16(aq, bk, f32x4{0.f,0.f,0.f,0.f}, 0, 0, 0);
    }
    const float scale = 0.17677669529663687f;
    float mx[4] = {-1e30f, -1e30f, -1e30f, -1e30f};
    #pragma unroll
    for (int n = 0; n < 16; ++n)
        #pragma unroll
        for (int r = 0; r < 4; ++r) { s[n][r] *= scale; mx[r] = fmaxf(mx[r], s[n][r]); }
    #pragma unroll
    for (int m = 1; m <= 8; m <<= 1)
        #pragma unroll
        for (int r = 0; r < 4; ++r) mx[r] = fmaxf(mx[r], __shfl_xor(mx[r], m));
    float sm[4] = {0.f, 0.f, 0.f, 0.f};
    #pragma unroll
    for (int n = 0; n < 16; ++n)
        #pragma unroll
        for (int r = 0; r < 4; ++r) {
            const float e = __expf(s[n][r] - mx[r]);
            s[n][r] = e; sm[r] += e;
        }
    #pragma unroll
    for (int m = 1; m <= 8; m <<= 1)
        #pragma unroll
        for (int r = 0; r < 4; ++r) sm[r] += __shfl_xor(sm[r], m);
    #pragma unroll
    for (int n = 0; n < 16; ++n)
        #pragma unroll
        for (int r = 0; r < 4; ++r)
            Pls[(w * 16 + fq * 4 + r) * 264 + n * 16 + fr] = f2bf(s[n][r]);
    __syncthreads();

    f32x4 o[2] = {f32x4{0.f,0.f,0.f,0.f}, f32x4{0.f,0.f,0.f,0.f}};
    #pragma unroll
    for (int kk = 0; kk < 8; ++kk) {
        const bf16x8 ap = *(const bf16x8*)&Pls[(w * 16 + fr) * 264 + kk * 32 + fq * 8];
        #pragma unroll
        for (int n = 0; n < 2; ++n) {
            const bf16x8 bv = *(const bf16x8*)&Vls[(n * 16 + fr) * 264 + kk * 32 + fq * 8];
            o[n] = __builtin_amdgcn_mfma_f32_16x16x32_bf16(ap, bv, o[n], 0, 0, 0);
        }
    }
    float inv[4];
    #pragma unroll
    for (int r = 0; r < 4; ++r) inv[r] = 1.0f / sm[r];
    #pragma unroll
    for (int n = 0; n < 2; ++n)
        #pragma unroll
        for (int r = 0; r < 4; ++r)
            O[((long)(b * 2048 + n0 + w * 16 + fq * 4 + r)) * 256 + h * 32 + n * 16 + fr] =
                f2bf(o[n][r] * inv[r]);
}

// ---------------- final head ----------------
__global__ __launch_bounds__(256)
void out_kernel(const float* __restrict__ H, const float* __restrict__ Wout,
                const float* __restrict__ bout, float* __restrict__ out)
{
    const int row = blockIdx.x * 4 + (threadIdx.x >> 6);
    const int lane = threadIdx.x & 63;
    float4 hv = *(const float4*)&H[(long)row * 256 + lane * 4];
    float4 wv = *(const float4*)&Wout[lane * 4];
    float s = hv.x * wv.x + hv.y * wv.y + hv.z * wv.z + hv.w * wv.w;
    #pragma unroll
    for (int m = 32; m >= 1; m >>= 1) s += __shfl_xor(s, m);
    if (lane == 0) out[row] = s + bout[0];
}

extern "C" void kernel_launch(void* const* d_in, const int* in_sizes, int n_in,
                              void* d_out, int out_size, void* d_ws, size_t ws_size,
                              hipStream_t stream)
{
    const float* x    = (const float*)d_in[0];
    const float* Wemb = (const float*)d_in[1];
    const float* bemb = (const float*)d_in[2];
    const float* pos  = (const float*)d_in[3];
    const float* ln0g = (const float*)d_in[4];
    const float* ln0b = (const float*)d_in[5];
    const float* ln1g = (const float*)d_in[6];
    const float* ln1b = (const float*)d_in[7];
    const float* Wq   = (const float*)d_in[8];
    const float* Wk   = (const float*)d_in[9];
    const float* Wv   = (const float*)d_in[10];
    const float* Ek   = (const float*)d_in[11];
    const float* Ev   = (const float*)d_in[12];
    const float* Wo   = (const float*)d_in[13];
    const float* bo   = (const float*)d_in[14];
    const float* ln2g = (const float*)d_in[15];
    const float* ln2b = (const float*)d_in[16];
    const float* W1   = (const float*)d_in[17];
    const float* b1   = (const float*)d_in[18];
    const float* W2   = (const float*)d_in[19];
    const float* b2   = (const float*)d_in[20];
    const float* Wout = (const float*)d_in[21];
    const float* bout = (const float*)d_in[22];

    char* ws = (char*)d_ws;
    float*  h    = (float*)(ws + 0);                    // 33.5 MB
    ushort* abf  = (ushort*)(ws + 33554432L);           // 16.8 MB  [32768,256] bf16
    ushort* aT   = (ushort*)(ws + 50331648L);           // 16.8 MB  [16][256][2048] bf16
    ushort* qbf  = (ushort*)(ws + 67108864L);           // 33.5 MB  q bf16 / FFN hidden chunk0 [32768,512]
    ushort* apkv = (ushort*)(ws + 100663296L);          //  4.2 MB  [16][512][256] bf16
    ushort* kp   = (ushort*)(ws + 104857600L);          //  2.1 MB  [16][256][256] bf16 (row=key)
    ushort* vpT  = (ushort*)(ws + 109051904L);          //  2.1 MB  [16][256][256] bf16 (row=d)
    ushort* WT   = (ushort*)(ws + 113246208L);          // 14.7 MB
    ushort* WqT  = WT;
    ushort* WkT  = WT + 262144;
    ushort* WvT  = WT + 524288;
    ushort* WoT  = WT + 786432;
    ushort* W1T  = WT + 1048576;
    ushort* W2T  = WT + 2097152;
    ushort* EkvT = WT + 3145728;
    // optional second FFN hidden chunk (33.5 MB) beyond the fixed 128 MB layout
    const bool bigws = (ws_size >= 161480704UL);
    ushort* hid0 = qbf;
    ushort* hid1 = (ushort*)(ws + 127926272L);
    float* outp = (float*)d_out;

    transpose_cast<<<dim3(8, 8, 4), 256, 0, stream>>>(Wq, WqT, 256, 256, 65536, 65536);
    transpose_cast<<<dim3(8, 8, 4), 256, 0, stream>>>(Wk, WkT, 256, 256, 65536, 65536);
    transpose_cast<<<dim3(8, 8, 4), 256, 0, stream>>>(Wv, WvT, 256, 256, 65536, 65536);
    transpose_cast<<<dim3(8, 8, 4), 256, 0, stream>>>(Wo, WoT, 256, 256, 65536, 65536);
    transpose_cast<<<dim3(32, 8, 4), 256, 0, stream>>>(W1, W1T, 256, 1024, 262144, 262144);
    transpose_cast<<<dim3(8, 32, 4), 256, 0, stream>>>(W2, W2T, 1024, 256, 262144, 262144);
    transpose_cast<<<dim3(8, 64, 4), 256, 0, stream>>>(Ek, EkvT, 2048, 256, 524288, 1048576);
    transpose_cast<<<dim3(8, 64, 4), 256, 0, stream>>>(Ev, EkvT + 524288, 2048, 256, 524288, 1048576);

    embed_ln2<<<8192, 256, 0, stream>>>(x, Wemb, bemb, pos, ln0g, ln0b, h);

    for (int i = 0; i < 4; ++i) {
        const ushort* WqT_i = WqT + i * 65536;
        const ushort* WkT_i = WkT + i * 65536;
        const ushort* WvT_i = WvT + i * 65536;
        const ushort* WoT_i = WoT + i * 65536;
        const ushort* W1T_i = W1T + i * 262144;
        const ushort* W2T_i = W2T + i * 262144;
        const ushort* EkvT_i = EkvT + (long)i * 1048576;

        // a = LN1(h) -> bf16 ; aT = transpose(a)
        ln_kernel<<<8192, 256, 0, stream>>>(h, ln1g + i * 256, ln1b + i * 256, abf);
        transpose_act<<<dim3(8, 1024), 256, 0, stream>>>(abf, aT);
        // q = a @ Wq  (bf16 out) — MT=64, 1024 blocks
        gemm_bf16<1,0,0,0,64,0><<<dim3(512, 2, 1), 256, 0, stream>>>(abf, WqT_i, nullptr, qbf,
            256, 256, 256, 256, 0, 0, 0, nullptr, 0);
        // apkv[b] = [Ek^T; Ev^T] @ a[b]  (bf16 out)
        gemm_bf16<1,0,0,0,64,0><<<dim3(8, 2, 16), 256, 0, stream>>>(EkvT_i, aT, nullptr, apkv,
            2048, 2048, 2048, 256, 0, 524288, 131072, nullptr, 0);
        // kp[b] = apk[b] @ Wk (bf16, row=key)
        gemm_bf16<1,0,0,0,64,0><<<dim3(4, 2, 16), 256, 0, stream>>>(apkv, WkT_i, nullptr, kp,
            256, 256, 256, 256, 131072, 0, 65536, nullptr, 0);
        // vpT[b] = Wv^T @ apv[b]^T  (bf16, row=d, col=key)
        gemm_bf16<1,0,0,0,64,0><<<dim3(4, 2, 16), 256, 0, stream>>>(WvT_i, apkv + 65536, nullptr, vpT,
            256, 256, 256, 256, 0, 131072, 65536, nullptr, 0);
        // fused MFMA attention -> abf (bf16)
        attn_mfma<<<dim3(32, 8, 16), 256, 0, stream>>>(qbf, kp, vpT, abf);
        // h += attnout @ Wo + bo — MT=64, 1024 blocks
        gemm_bf16<0,1,0,1,64,0><<<dim3(512, 2, 1), 256, 0, stream>>>(abf, WoT_i, bo + i * 256, h,
            256, 256, 256, 256, 0, 0, 0, nullptr, 0);
        // a = LN2(h)
        ln_kernel<<<8192, 256, 0, stream>>>(h, ln2g + i * 256, ln2b + i * 256, abf);
        if (bigws) {
            // hidden = gelu(a @ W1 + b1) in two 512-wide chunks (separate buffers)
            gemm_bf16<1,0,1,1,128,0><<<dim3(256, 4, 1), 256, 0, stream>>>(abf, W1T_i,
                b1 + (long)i * 1024, hid0, 256, 256, 256, 512, 0, 0, 0, nullptr, 0);
            gemm_bf16<1,0,1,1,128,0><<<dim3(256, 4, 1), 256, 0, stream>>>(abf, W1T_i + 131072,
                b1 + (long)i * 1024 + 512, hid1, 256, 256, 256, 512, 0, 0, 0, nullptr, 0);
            // h += hidden @ W2 + b2 — single pass, Kd=1024 over both chunks
            gemm_bf16<0,1,0,1,64,1><<<dim3(512, 2, 1), 256, 0, stream>>>(hid0, W2T_i,
                b2 + i * 256, h, 1024, 512, 1024, 256, 0, 0, 0, hid1, 512);
        } else {
            for (int c = 0; c < 2; ++c) {
                gemm_bf16<1,0,1,1,128,0><<<dim3(256, 4, 1), 256, 0, stream>>>(abf, W1T_i + c * 131072,
                    b1 + (long)i * 1024 + c * 512, qbf,
                    256, 256, 256, 512, 0, 0, 0, nullptr, 0);
                if (c == 0)
                    gemm_bf16<0,1,0,1,64,0><<<dim3(512, 2, 1), 256, 0, stream>>>(qbf,
                        W2T_i + c * 512, b2 + i * 256, h, 512, 512, 1024, 256, 0, 0, 0, nullptr, 0);
                else
                    gemm_bf16<0,1,0,0,64,0><<<dim3(512, 2, 1), 256, 0, stream>>>(qbf,
                        W2T_i + c * 512, nullptr, h, 512, 512, 1024, 256, 0, 0, 0, nullptr, 0);
            }
        }
    }
    out_kernel<<<8192, 256, 0, stream>>>(h, Wout, bout, outp);
}

// Round 7
// 1005.316 us; speedup vs baseline: 1.0636x; 1.0044x over previous
//
#include <hip/hip_runtime.h>
#include <hip/hip_bf16.h>

// Model dims: B=16, N=2048, F=40, D=256, H=8, K=256, L=4, DH=32
// fp32 inputs/outputs; bf16 MFMA GEMMs + attention; fp32 residual stream with
// streaming delta-writes (no RMW in GEMM epilogues) + fused add+LN passes.

typedef short bf16x8 __attribute__((ext_vector_type(8)));
typedef float f32x4 __attribute__((ext_vector_type(4)));

#define GLOBAL_AS __attribute__((address_space(1)))
#define LDS_AS __attribute__((address_space(3)))

static __device__ __forceinline__ float gelu_f(float v) {
    return 0.5f * v * (1.0f + erff(v * 0.70710678118654752f));
}
static __device__ __forceinline__ ushort f2bf(float x) {
    __hip_bfloat16 h = __float2bfloat16(x);
    return __builtin_bit_cast(ushort, h);
}
static __device__ __forceinline__ float bf2f(ushort u) {
    unsigned int x = ((unsigned int)u) << 16;
    return __builtin_bit_cast(float, x);
}

// ---------------- embed + pos + LN0: wave-per-row ----------------
__global__ __launch_bounds__(256)
void embed_ln2(const float* __restrict__ x, const float* __restrict__ Wemb,
               const float* __restrict__ bemb, const float* __restrict__ pos,
               const float* __restrict__ g0, const float* __restrict__ b0,
               float* __restrict__ H)
{
    const int t = threadIdx.x, w = t >> 6, l = t & 63;
    const long row = (long)blockIdx.x * 4 + w;
    const int n = (int)(row & 2047);
    const float xl = (l < 40) ? x[row * 40 + l] : 0.f;
    float4 acc = *(const float4*)&bemb[l * 4];
    const float4 pv = *(const float4*)&pos[(long)n * 256 + l * 4];
    acc.x += pv.x; acc.y += pv.y; acc.z += pv.z; acc.w += pv.w;
    #pragma unroll 8
    for (int f = 0; f < 40; ++f) {
        const float xf = __shfl(xl, f);
        const float4 wv = *(const float4*)&Wemb[f * 256 + l * 4];
        acc.x += xf * wv.x; acc.y += xf * wv.y; acc.z += xf * wv.z; acc.w += xf * wv.w;
    }
    float s = acc.x + acc.y + acc.z + acc.w;
    #pragma unroll
    for (int m = 32; m >= 1; m >>= 1) s += __shfl_xor(s, m);
    const float mean = s * (1.0f / 256.0f);
    const float dx = acc.x - mean, dy = acc.y - mean, dz = acc.z - mean, dw = acc.w - mean;
    float q = dx * dx + dy * dy + dz * dz + dw * dw;
    #pragma unroll
    for (int m = 32; m >= 1; m >>= 1) q += __shfl_xor(q, m);
    const float inv = rsqrtf(q * (1.0f / 256.0f) + 1e-5f);
    const float4 gv = *(const float4*)&g0[l * 4];
    const float4 bv = *(const float4*)&b0[l * 4];
    float4 y;
    y.x = dx * inv * gv.x + bv.x;
    y.y = dy * inv * gv.y + bv.y;
    y.z = dz * inv * gv.z + bv.z;
    y.w = dw * inv * gv.w + bv.w;
    *(float4*)&H[row * 256 + l * 4] = y;
}

// ---------------- LayerNorm fp32 -> bf16 (layer-0 LN1 only) ----------------
__global__ __launch_bounds__(256)
void ln_kernel(const float* __restrict__ X, const float* __restrict__ g,
               const float* __restrict__ b, ushort* __restrict__ Y)
{
    const int row = blockIdx.x * 4 + (threadIdx.x >> 6);
    const int lane = threadIdx.x & 63;
    const long base = (long)row * 256 + lane * 4;
    float4 xv = *(const float4*)&X[base];
    float s = xv.x + xv.y + xv.z + xv.w;
    #pragma unroll
    for (int m = 32; m >= 1; m >>= 1) s += __shfl_xor(s, m);
    const float mean = s * (1.0f / 256.0f);
    const float dx = xv.x - mean, dy = xv.y - mean, dz = xv.z - mean, dw = xv.w - mean;
    float q = dx * dx + dy * dy + dz * dz + dw * dw;
    #pragma unroll
    for (int m = 32; m >= 1; m >>= 1) q += __shfl_xor(q, m);
    const float inv = rsqrtf(q * (1.0f / 256.0f) + 1e-5f);
    const float4 gv = *(const float4*)&g[lane * 4];
    const float4 bv = *(const float4*)&b[lane * 4];
    ushort4 y;
    y.x = f2bf(dx * inv * gv.x + bv.x);
    y.y = f2bf(dy * inv * gv.y + bv.y);
    y.z = f2bf(dz * inv * gv.z + bv.z);
    y.w = f2bf(dw * inv * gv.w + bv.w);
    *(ushort4*)&Y[base] = y;
}

// ---------------- fused residual add + optional LayerNorm ----------------
// h += delta + cbias ; if HASLN: Y = LN(h_new)*g + b  (bf16).
// delta may alias Y (per-element read-before-write within the owning thread).
template<int HASLN, int DBF>
__global__ __launch_bounds__(256)
void add_ln(float* __restrict__ H, const void* delta, const float* __restrict__ cbias,
            const float* __restrict__ g, const float* __restrict__ b, ushort* Y)
{
    const int row = blockIdx.x * 4 + (threadIdx.x >> 6);
    const int lane = threadIdx.x & 63;
    const long base = (long)row * 256 + lane * 4;
    float4 hv = *(const float4*)&H[base];
    float4 dv;
    if (DBF) {
        const ushort4 du = *(const ushort4*)&((const ushort*)delta)[base];
        dv.x = bf2f(du.x); dv.y = bf2f(du.y); dv.z = bf2f(du.z); dv.w = bf2f(du.w);
    } else {
        dv = *(const float4*)&((const float*)delta)[base];
    }
    const float4 cb = *(const float4*)&cbias[lane * 4];
    hv.x += dv.x + cb.x; hv.y += dv.y + cb.y;
    hv.z += dv.z + cb.z; hv.w += dv.w + cb.w;
    *(float4*)&H[base] = hv;
    if (HASLN) {
        float s = hv.x + hv.y + hv.z + hv.w;
        #pragma unroll
        for (int m = 32; m >= 1; m >>= 1) s += __shfl_xor(s, m);
        const float mean = s * (1.0f / 256.0f);
        const float dx = hv.x - mean, dy = hv.y - mean, dz = hv.z - mean, dw = hv.w - mean;
        float q = dx * dx + dy * dy + dz * dz + dw * dw;
        #pragma unroll
        for (int m = 32; m >= 1; m >>= 1) q += __shfl_xor(q, m);
        const float inv = rsqrtf(q * (1.0f / 256.0f) + 1e-5f);
        const float4 gv = *(const float4*)&g[lane * 4];
        const float4 bv = *(const float4*)&b[lane * 4];
        ushort4 y;
        y.x = f2bf(dx * inv * gv.x + bv.x);
        y.y = f2bf(dy * inv * gv.y + bv.y);
        y.z = f2bf(dz * inv * gv.z + bv.z);
        y.w = f2bf(dw * inv * gv.w + bv.w);
        *(ushort4*)&Y[base] = y;
    }
}

// ---------------- weight transpose + cast ----------------
__global__ __launch_bounds__(256)
void transpose_cast(const float* __restrict__ in, ushort* __restrict__ out,
                    int R, int C, long sIn, long sOut)
{
    __shared__ float tile[32][33];
    in += (long)blockIdx.z * sIn; out += (long)blockIdx.z * sOut;
    const int c0 = blockIdx.x * 32, r0 = blockIdx.y * 32;
    const int tx = threadIdx.x & 31, ty = threadIdx.x >> 5;
    #pragma unroll
    for (int j = 0; j < 4; ++j)
        tile[ty + j * 8][tx] = in[(long)(r0 + ty + j * 8) * C + c0 + tx];
    __syncthreads();
    #pragma unroll
    for (int j = 0; j < 4; ++j)
        out[(long)(c0 + ty + j * 8) * R + r0 + tx] = f2bf(tile[tx][ty + j * 8]);
}

// ---------------- activation transpose: abf [32768,256] -> aT [16][256][2048] ----------------
__global__ __launch_bounds__(256)
void transpose_act(const ushort* __restrict__ in, ushort* __restrict__ out)
{
    __shared__ ushort tile[32][33];
    const int c0 = blockIdx.x * 32, r0 = blockIdx.y * 32;
    const int tx = threadIdx.x & 31, ty = threadIdx.x >> 5;
    #pragma unroll
    for (int j = 0; j < 4; ++j)
        tile[ty + j * 8][tx] = in[(long)(r0 + ty + j * 8) * 256 + c0 + tx];
    __syncthreads();
    const int b = r0 >> 11, nn = r0 & 2047;
    #pragma unroll
    for (int j = 0; j < 4; ++j)
        out[((long)(b * 256 + c0 + ty + j * 8)) * 2048 + nn + tx] = tile[tx][ty + j * 8];
}

// ---------------- bf16 MFMA GEMM, m97 structure + 2-phase prefetch ----------------
// C[bz] = op( A[bz] @ BT[bz]^T ) — A [M,Kd] bf16, BT [N,Kd] bf16.
// MT=128: 128x128 tile, 4 waves 2x2 (4x4 frags). MT=64: 64x128, 4 waves 1x4 (4x2 frags).
// Double-buffered LDS; next K-tile staged before current tile's MFMA.
template<int OBF16, int ACT, int HASB, int MT>
__global__ __launch_bounds__(256)
void gemm_bf16(const ushort* __restrict__ A, const ushort* __restrict__ BT,
               const float* __restrict__ bias, void* __restrict__ Cout,
               int Kd, int lda, int ldb, int ldc,
               long sA, long sBT, long sC)
{
    constexpr int NF  = (MT == 128) ? 4 : 2;
    constexpr int CPW = (MT == 128) ? 64 : 32;
    __shared__ ushort Als[2][MT * 32];
    __shared__ ushort Bls[2][128 * 32];
    const int bz = blockIdx.z;
    const ushort* Ab = A + (long)bz * sA;
    const ushort* Bb = BT + (long)bz * sBT;
    const int m0 = blockIdx.x * MT, n0 = blockIdx.y * 128;
    const int t = threadIdx.x, l = t & 63, w = t >> 6;
    const int wr = (MT == 128) ? (w >> 1) : 0;
    const int wc = (MT == 128) ? (w & 1) : w;
    const int fr = l & 15, fq = l >> 4;

    f32x4 acc[4][NF];
    #pragma unroll
    for (int m = 0; m < 4; ++m)
        #pragma unroll
        for (int n = 0; n < NF; ++n) acc[m][n] = f32x4{0.f, 0.f, 0.f, 0.f};

    const int srow = t >> 2;
    const int skcol = (t & 3) * 8;
    const int dst0 = w * 512;
    const ushort* Abase = Ab + (long)(m0 + srow) * lda + skcol;
    const ushort* Bbase = Bb + (long)(n0 + srow) * ldb + skcol;

    auto stage = [&](int kk, int bf) {
        const ushort* ag = Abase + kk;
        const ushort* bg = Bbase + kk;
        __builtin_amdgcn_global_load_lds((const GLOBAL_AS void*)ag,
                                         (LDS_AS void*)&Als[bf][dst0], 16, 0, 0);
        if constexpr (MT == 128)
            __builtin_amdgcn_global_load_lds((const GLOBAL_AS void*)(ag + (long)64 * lda),
                                             (LDS_AS void*)&Als[bf][2048 + dst0], 16, 0, 0);
        __builtin_amdgcn_global_load_lds((const GLOBAL_AS void*)bg,
                                         (LDS_AS void*)&Bls[bf][dst0], 16, 0, 0);
        __builtin_amdgcn_global_load_lds((const GLOBAL_AS void*)(bg + (long)64 * ldb),
                                         (LDS_AS void*)&Bls[bf][2048 + dst0], 16, 0, 0);
    };

    stage(0, 0);
    __syncthreads();                    // drains vmcnt(0) per barrier semantics
    int cur = 0;
    for (int kk = 0; kk < Kd; kk += 32) {
        if (kk + 32 < Kd) stage(kk + 32, cur ^ 1);   // prefetch next tile
        bf16x8 af[4], bfv[NF];
        #pragma unroll
        for (int m = 0; m < 4; ++m)
            af[m] = *(const bf16x8*)&Als[cur][(wr * 64 + m * 16 + fr) * 32 + fq * 8];
        #pragma unroll
        for (int n = 0; n < NF; ++n)
            bfv[n] = *(const bf16x8*)&Bls[cur][(wc * CPW + n * 16 + fr) * 32 + fq * 8];
        #pragma unroll
        for (int m = 0; m < 4; ++m)
            #pragma unroll
            for (int n = 0; n < NF; ++n)
                acc[m][n] = __builtin_amdgcn_mfma_f32_16x16x32_bf16(af[m], bfv[n], acc[m][n], 0, 0, 0);
        __syncthreads();                // drains prefetch + protects buffer reuse
        cur ^= 1;
    }

    float bsv[NF];
    #pragma unroll
    for (int n = 0; n < NF; ++n) bsv[n] = HASB ? bias[n0 + wc * CPW + n * 16 + fr] : 0.f;
    #pragma unroll
    for (int m = 0; m < 4; ++m) {
        #pragma unroll
        for (int r = 0; r < 4; ++r) {
            const int grow = m0 + wr * 64 + m * 16 + fq * 4 + r;
            const long rowoff = (long)grow * ldc + n0 + wc * CPW + fr;
            #pragma unroll
            for (int n = 0; n < NF; ++n) {
                float v = acc[m][n][r] + bsv[n];
                if (ACT) v = gelu_f(v);
                const long off = rowoff + n * 16;
                if (OBF16) ((ushort*)Cout)[(long)bz * sC + off] = f2bf(v);
                else       ((float*)Cout)[(long)bz * sC + off] = v;
            }
        }
    }
}

// ---------------- fused MFMA attention ----------------
__global__ __launch_bounds__(256)
void attn_mfma(const ushort* __restrict__ Q, const ushort* __restrict__ Kp,
               const ushort* __restrict__ VpT, ushort* __restrict__ O)
{
    __shared__ ushort Qls[64 * 40];
    __shared__ ushort Kls[256 * 40];
    __shared__ ushort Vls[32 * 264];
    __shared__ ushort Pls[64 * 264];
    const int qt = blockIdx.x, h = blockIdx.y, b = blockIdx.z;
    const int n0 = qt * 64;
    const int t = threadIdx.x, w = t >> 6, l = t & 63;
    const int fr = l & 15, fq = l >> 4;

    {
        const int r = t >> 2, c = (t & 3) * 8;
        *(float4*)&Qls[r * 40 + c] =
            *(const float4*)&Q[((long)(b * 2048 + n0 + r)) * 256 + h * 32 + c];
    }
    #pragma unroll
    for (int it = 0; it < 4; ++it) {
        const int r = (t >> 2) + it * 64, c = (t & 3) * 8;
        *(float4*)&Kls[r * 40 + c] =
            *(const float4*)&Kp[((long)(b * 256 + r)) * 256 + h * 32 + c];
    }
    {
        const int r = t >> 3, c0 = (t & 7) * 32;
        const ushort* src = VpT + ((long)(b * 256 + h * 32 + r)) * 256 + c0;
        #pragma unroll
        for (int j = 0; j < 4; ++j)
            *(float4*)&Vls[r * 264 + c0 + j * 8] = *(const float4*)(src + j * 8);
    }
    __syncthreads();

    const bf16x8 aq = *(const bf16x8*)&Qls[(w * 16 + fr) * 40 + fq * 8];
    f32x4 s[16];
    #pragma unroll
    for (int n = 0; n < 16; ++n) {
        const bf16x8 bk = *(const bf16x8*)&Kls[(n * 16 + fr) * 40 + fq * 8];
        s[n] = __builtin_amdgcn_mfma_f32_16x16x32_bf16(aq, bk, f32x4{0.f,0.f,0.f,0.f}, 0, 0, 0);
    }
    const float scale = 0.17677669529663687f;
    float mx[4] = {-1e30f, -1e30f, -1e30f, -1e30f};
    #pragma unroll
    for (int n = 0; n < 16; ++n)
        #pragma unroll
        for (int r = 0; r < 4; ++r) { s[n][r] *= scale; mx[r] = fmaxf(mx[r], s[n][r]); }
    #pragma unroll
    for (int m = 1; m <= 8; m <<= 1)
        #pragma unroll
        for (int r = 0; r < 4; ++r) mx[r] = fmaxf(mx[r], __shfl_xor(mx[r], m));
    float sm[4] = {0.f, 0.f, 0.f, 0.f};
    #pragma unroll
    for (int n = 0; n < 16; ++n)
        #pragma unroll
        for (int r = 0; r < 4; ++r) {
            const float e = __expf(s[n][r] - mx[r]);
            s[n][r] = e; sm[r] += e;
        }
    #pragma unroll
    for (int m = 1; m <= 8; m <<= 1)
        #pragma unroll
        for (int r = 0; r < 4; ++r) sm[r] += __shfl_xor(sm[r], m);
    #pragma unroll
    for (int n = 0; n < 16; ++n)
        #pragma unroll
        for (int r = 0; r < 4; ++r)
            Pls[(w * 16 + fq * 4 + r) * 264 + n * 16 + fr] = f2bf(s[n][r]);
    __syncthreads();

    f32x4 o[2] = {f32x4{0.f,0.f,0.f,0.f}, f32x4{0.f,0.f,0.f,0.f}};
    #pragma unroll
    for (int kk = 0; kk < 8; ++kk) {
        const bf16x8 ap = *(const bf16x8*)&Pls[(w * 16 + fr) * 264 + kk * 32 + fq * 8];
        #pragma unroll
        for (int n = 0; n < 2; ++n) {
            const bf16x8 bv = *(const bf16x8*)&Vls[(n * 16 + fr) * 264 + kk * 32 + fq * 8];
            o[n] = __builtin_amdgcn_mfma_f32_16x16x32_bf16(ap, bv, o[n], 0, 0, 0);
        }
    }
    float inv[4];
    #pragma unroll
    for (int r = 0; r < 4; ++r) inv[r] = 1.0f / sm[r];
    #pragma unroll
    for (int n = 0; n < 2; ++n)
        #pragma unroll
        for (int r = 0; r < 4; ++r)
            O[((long)(b * 2048 + n0 + w * 16 + fq * 4 + r)) * 256 + h * 32 + n * 16 + fr] =
                f2bf(o[n][r] * inv[r]);
}

// ---------------- final head ----------------
__global__ __launch_bounds__(256)
void out_kernel(const float* __restrict__ H, const float* __restrict__ Wout,
                const float* __restrict__ bout, float* __restrict__ out)
{
    const int row = blockIdx.x * 4 + (threadIdx.x >> 6);
    const int lane = threadIdx.x & 63;
    float4 hv = *(const float4*)&H[(long)row * 256 + lane * 4];
    float4 wv = *(const float4*)&Wout[lane * 4];
    float s = hv.x * wv.x + hv.y * wv.y + hv.z * wv.z + hv.w * wv.w;
    #pragma unroll
    for (int m = 32; m >= 1; m >>= 1) s += __shfl_xor(s, m);
    if (lane == 0) out[row] = s + bout[0];
}

extern "C" void kernel_launch(void* const* d_in, const int* in_sizes, int n_in,
                              void* d_out, int out_size, void* d_ws, size_t ws_size,
                              hipStream_t stream)
{
    const float* x    = (const float*)d_in[0];
    const float* Wemb = (const float*)d_in[1];
    const float* bemb = (const float*)d_in[2];
    const float* pos  = (const float*)d_in[3];
    const float* ln0g = (const float*)d_in[4];
    const float* ln0b = (const float*)d_in[5];
    const float* ln1g = (const float*)d_in[6];
    const float* ln1b = (const float*)d_in[7];
    const float* Wq   = (const float*)d_in[8];
    const float* Wk   = (const float*)d_in[9];
    const float* Wv   = (const float*)d_in[10];
    const float* Ek   = (const float*)d_in[11];
    const float* Ev   = (const float*)d_in[12];
    const float* Wo   = (const float*)d_in[13];
    const float* bo   = (const float*)d_in[14];
    const float* ln2g = (const float*)d_in[15];
    const float* ln2b = (const float*)d_in[16];
    const float* W1   = (const float*)d_in[17];
    const float* b1   = (const float*)d_in[18];
    const float* W2   = (const float*)d_in[19];
    const float* b2   = (const float*)d_in[20];
    const float* Wout = (const float*)d_in[21];
    const float* bout = (const float*)d_in[22];

    // Workspace layout (lifetime-overlapped; peak 132,120,576 B <= 128 MiB):
    //   h    f32 [32768,256]         @ 0          (33.5 MB, persistent)
    //   abf  bf16 [32768,256]        @ 33,554,432 (16.8 MB; also W2-delta)
    //   aT   bf16 [16][256][2048]    @ 50,331,648 (16.8 MB)
    //   kp   bf16 [16][256][256]     @ 67,108,864 ( 2.1 MB)  \
    //   vpT  bf16 [16][256][256]     @ 69,206,016 ( 2.1 MB)  | dbuf f32 [32768,256]
    //   apkv bf16 [16][512][256]     @ 71,303,168 ( 4.2 MB)  | @67,108,864 overlaps
    //   qbf  bf16 [32768,256]        @ 100,663,296 (16.8 MB)
    //   hid  bf16 [32768,1024]       @ 50,331,648 (67.1 MB; overlaps aT..qbf)
    //   WT   bf16 weights            @ 117,440,512 (14.7 MB)
    char* ws = (char*)d_ws;
    float*  h    = (float*)(ws + 0);
    ushort* abf  = (ushort*)(ws + 33554432L);
    ushort* aT   = (ushort*)(ws + 50331648L);
    ushort* kp   = (ushort*)(ws + 67108864L);
    ushort* vpT  = (ushort*)(ws + 69206016L);
    ushort* apkv = (ushort*)(ws + 71303168L);
    float*  dbuf = (float*)(ws + 67108864L);
    ushort* qbf  = (ushort*)(ws + 100663296L);
    ushort* hid  = (ushort*)(ws + 50331648L);
    ushort* WT   = (ushort*)(ws + 117440512L);
    ushort* WqT  = WT;
    ushort* WkT  = WT + 262144;
    ushort* WvT  = WT + 524288;
    ushort* WoT  = WT + 786432;
    ushort* W1T  = WT + 1048576;
    ushort* W2T  = WT + 2097152;
    ushort* EkvT = WT + 3145728;
    float* outp = (float*)d_out;

    transpose_cast<<<dim3(8, 8, 4), 256, 0, stream>>>(Wq, WqT, 256, 256, 65536, 65536);
    transpose_cast<<<dim3(8, 8, 4), 256, 0, stream>>>(Wk, WkT, 256, 256, 65536, 65536);
    transpose_cast<<<dim3(8, 8, 4), 256, 0, stream>>>(Wv, WvT, 256, 256, 65536, 65536);
    transpose_cast<<<dim3(8, 8, 4), 256, 0, stream>>>(Wo, WoT, 256, 256, 65536, 65536);
    transpose_cast<<<dim3(32, 8, 4), 256, 0, stream>>>(W1, W1T, 256, 1024, 262144, 262144);
    transpose_cast<<<dim3(8, 32, 4), 256, 0, stream>>>(W2, W2T, 1024, 256, 262144, 262144);
    transpose_cast<<<dim3(8, 64, 4), 256, 0, stream>>>(Ek, EkvT, 2048, 256, 524288, 1048576);
    transpose_cast<<<dim3(8, 64, 4), 256, 0, stream>>>(Ev, EkvT + 524288, 2048, 256, 524288, 1048576);

    embed_ln2<<<8192, 256, 0, stream>>>(x, Wemb, bemb, pos, ln0g, ln0b, h);
    ln_kernel<<<8192, 256, 0, stream>>>(h, ln1g, ln1b, abf);
    transpose_act<<<dim3(8, 1024), 256, 0, stream>>>(abf, aT);

    for (int i = 0; i < 4; ++i) {
        const ushort* WqT_i = WqT + i * 65536;
        const ushort* WkT_i = WkT + i * 65536;
        const ushort* WvT_i = WvT + i * 65536;
        const ushort* WoT_i = WoT + i * 65536;
        const ushort* W1T_i = W1T + i * 262144;
        const ushort* W2T_i = W2T + i * 262144;
        const ushort* EkvT_i = EkvT + (long)i * 1048576;

        // q = a @ Wq  (bf16 out)
        gemm_bf16<1,0,0,64><<<dim3(512, 2, 1), 256, 0, stream>>>(abf, WqT_i, nullptr, qbf,
            256, 256, 256, 256, 0, 0, 0);
        // apkv[b] = [Ek^T; Ev^T] @ a[b]  (bf16 out)
        gemm_bf16<1,0,0,64><<<dim3(8, 2, 16), 256, 0, stream>>>(EkvT_i, aT, nullptr, apkv,
            2048, 2048, 2048, 256, 0, 524288, 131072);
        // kp[b] = apk[b] @ Wk (bf16, row=key)
        gemm_bf16<1,0,0,64><<<dim3(4, 2, 16), 256, 0, stream>>>(apkv, WkT_i, nullptr, kp,
            256, 256, 256, 256, 131072, 0, 65536);
        // vpT[b] = Wv^T @ apv[b]^T  (bf16, row=d, col=key)
        gemm_bf16<1,0,0,64><<<dim3(4, 2, 16), 256, 0, stream>>>(WvT_i, apkv + 65536, nullptr, vpT,
            256, 256, 256, 256, 0, 131072, 65536);
        // fused MFMA attention -> abf (bf16)  [LN1 out dead now]
        attn_mfma<<<dim3(32, 8, 16), 256, 0, stream>>>(qbf, kp, vpT, abf);
        // delta_o = attnout @ Wo  (f32 streaming, no RMW)
        gemm_bf16<0,0,0,64><<<dim3(512, 2, 1), 256, 0, stream>>>(abf, WoT_i, nullptr, dbuf,
            256, 256, 256, 256, 0, 0, 0);
        // h += delta_o + bo ; abf = LN2(h)
        add_ln<1,0><<<8192, 256, 0, stream>>>(h, dbuf, bo + i * 256,
            ln2g + i * 256, ln2b + i * 256, abf);
        // hid[:, 0:512) and [512:1024) = gelu(a @ W1 + b1)
        gemm_bf16<1,1,1,128><<<dim3(256, 4, 1), 256, 0, stream>>>(abf, W1T_i,
            b1 + (long)i * 1024, hid, 256, 256, 256, 1024, 0, 0, 0);
        gemm_bf16<1,1,1,128><<<dim3(256, 4, 1), 256, 0, stream>>>(abf, W1T_i + 131072,
            b1 + (long)i * 1024 + 512, hid + 512, 256, 256, 256, 1024, 0, 0, 0);
        // delta_2 = hid @ W2  (bf16 streaming into abf region)
        gemm_bf16<1,0,0,64><<<dim3(512, 2, 1), 256, 0, stream>>>(hid, W2T_i, nullptr, abf,
            1024, 1024, 1024, 256, 0, 0, 0);
        if (i < 3) {
            // h += delta_2 + b2 ; abf = LN1[i+1](h) ; aT = transpose(abf)
            add_ln<1,1><<<8192, 256, 0, stream>>>(h, abf, b2 + i * 256,
                ln1g + (i + 1) * 256, ln1b + (i + 1) * 256, abf);
            transpose_act<<<dim3(8, 1024), 256, 0, stream>>>(abf, aT);
        } else {
            add_ln<0,1><<<8192, 256, 0, stream>>>(h, abf, b2 + i * 256,
                nullptr, nullptr, nullptr);
        }
    }
    out_kernel<<<8192, 256, 0, stream>>>(h, Wout, bout, outp);
}

// Round 8
// 971.988 us; speedup vs baseline: 1.1001x; 1.0343x over previous
//
#include <hip/hip_runtime.h>
#include <hip/hip_bf16.h>

// Model dims: B=16, N=2048, F=40, D=256, H=8, K=256, L=4, DH=32
// fp32 inputs/outputs; bf16 MFMA GEMMs + attention; fp32 residual stream with
// streaming bf16 delta-writes + fused add+LN passes.
// GEMM: 64x64x32 tiles, 4 waves (2x2 quadrants), single-buffer 8KB LDS,
// 2048-8192 blocks/dispatch -> 8 blocks/CU for cross-block latency hiding.

typedef short bf16x8 __attribute__((ext_vector_type(8)));
typedef float f32x4 __attribute__((ext_vector_type(4)));

#define GLOBAL_AS __attribute__((address_space(1)))
#define LDS_AS __attribute__((address_space(3)))

static __device__ __forceinline__ float gelu_f(float v) {
    return 0.5f * v * (1.0f + erff(v * 0.70710678118654752f));
}
static __device__ __forceinline__ ushort f2bf(float x) {
    __hip_bfloat16 h = __float2bfloat16(x);
    return __builtin_bit_cast(ushort, h);
}
static __device__ __forceinline__ float bf2f(ushort u) {
    unsigned int x = ((unsigned int)u) << 16;
    return __builtin_bit_cast(float, x);
}

// ---------------- embed + pos + LN0: wave-per-row ----------------
__global__ __launch_bounds__(256)
void embed_ln2(const float* __restrict__ x, const float* __restrict__ Wemb,
               const float* __restrict__ bemb, const float* __restrict__ pos,
               const float* __restrict__ g0, const float* __restrict__ b0,
               float* __restrict__ H)
{
    const int t = threadIdx.x, w = t >> 6, l = t & 63;
    const long row = (long)blockIdx.x * 4 + w;
    const int n = (int)(row & 2047);
    const float xl = (l < 40) ? x[row * 40 + l] : 0.f;
    float4 acc = *(const float4*)&bemb[l * 4];
    const float4 pv = *(const float4*)&pos[(long)n * 256 + l * 4];
    acc.x += pv.x; acc.y += pv.y; acc.z += pv.z; acc.w += pv.w;
    #pragma unroll 8
    for (int f = 0; f < 40; ++f) {
        const float xf = __shfl(xl, f);
        const float4 wv = *(const float4*)&Wemb[f * 256 + l * 4];
        acc.x += xf * wv.x; acc.y += xf * wv.y; acc.z += xf * wv.z; acc.w += xf * wv.w;
    }
    float s = acc.x + acc.y + acc.z + acc.w;
    #pragma unroll
    for (int m = 32; m >= 1; m >>= 1) s += __shfl_xor(s, m);
    const float mean = s * (1.0f / 256.0f);
    const float dx = acc.x - mean, dy = acc.y - mean, dz = acc.z - mean, dw = acc.w - mean;
    float q = dx * dx + dy * dy + dz * dz + dw * dw;
    #pragma unroll
    for (int m = 32; m >= 1; m >>= 1) q += __shfl_xor(q, m);
    const float inv = rsqrtf(q * (1.0f / 256.0f) + 1e-5f);
    const float4 gv = *(const float4*)&g0[l * 4];
    const float4 bv = *(const float4*)&b0[l * 4];
    float4 y;
    y.x = dx * inv * gv.x + bv.x;
    y.y = dy * inv * gv.y + bv.y;
    y.z = dz * inv * gv.z + bv.z;
    y.w = dw * inv * gv.w + bv.w;
    *(float4*)&H[row * 256 + l * 4] = y;
}

// ---------------- LayerNorm fp32 -> bf16 (layer-0 LN1 only) ----------------
__global__ __launch_bounds__(256)
void ln_kernel(const float* __restrict__ X, const float* __restrict__ g,
               const float* __restrict__ b, ushort* __restrict__ Y)
{
    const int row = blockIdx.x * 4 + (threadIdx.x >> 6);
    const int lane = threadIdx.x & 63;
    const long base = (long)row * 256 + lane * 4;
    float4 xv = *(const float4*)&X[base];
    float s = xv.x + xv.y + xv.z + xv.w;
    #pragma unroll
    for (int m = 32; m >= 1; m >>= 1) s += __shfl_xor(s, m);
    const float mean = s * (1.0f / 256.0f);
    const float dx = xv.x - mean, dy = xv.y - mean, dz = xv.z - mean, dw = xv.w - mean;
    float q = dx * dx + dy * dy + dz * dz + dw * dw;
    #pragma unroll
    for (int m = 32; m >= 1; m >>= 1) q += __shfl_xor(q, m);
    const float inv = rsqrtf(q * (1.0f / 256.0f) + 1e-5f);
    const float4 gv = *(const float4*)&g[lane * 4];
    const float4 bv = *(const float4*)&b[lane * 4];
    ushort4 y;
    y.x = f2bf(dx * inv * gv.x + bv.x);
    y.y = f2bf(dy * inv * gv.y + bv.y);
    y.z = f2bf(dz * inv * gv.z + bv.z);
    y.w = f2bf(dw * inv * gv.w + bv.w);
    *(ushort4*)&Y[base] = y;
}

// ---------------- fused residual add + optional LayerNorm ----------------
template<int HASLN>
__global__ __launch_bounds__(256)
void add_ln(float* __restrict__ H, const ushort* __restrict__ delta,
            const float* __restrict__ cbias,
            const float* __restrict__ g, const float* __restrict__ b, ushort* Y)
{
    const int row = blockIdx.x * 4 + (threadIdx.x >> 6);
    const int lane = threadIdx.x & 63;
    const long base = (long)row * 256 + lane * 4;
    float4 hv = *(const float4*)&H[base];
    const ushort4 du = *(const ushort4*)&delta[base];
    const float4 cb = *(const float4*)&cbias[lane * 4];
    hv.x += bf2f(du.x) + cb.x; hv.y += bf2f(du.y) + cb.y;
    hv.z += bf2f(du.z) + cb.z; hv.w += bf2f(du.w) + cb.w;
    *(float4*)&H[base] = hv;
    if (HASLN) {
        float s = hv.x + hv.y + hv.z + hv.w;
        #pragma unroll
        for (int m = 32; m >= 1; m >>= 1) s += __shfl_xor(s, m);
        const float mean = s * (1.0f / 256.0f);
        const float dx = hv.x - mean, dy = hv.y - mean, dz = hv.z - mean, dw = hv.w - mean;
        float q = dx * dx + dy * dy + dz * dz + dw * dw;
        #pragma unroll
        for (int m = 32; m >= 1; m >>= 1) q += __shfl_xor(q, m);
        const float inv = rsqrtf(q * (1.0f / 256.0f) + 1e-5f);
        const float4 gv = *(const float4*)&g[lane * 4];
        const float4 bv = *(const float4*)&b[lane * 4];
        ushort4 y;
        y.x = f2bf(dx * inv * gv.x + bv.x);
        y.y = f2bf(dy * inv * gv.y + bv.y);
        y.z = f2bf(dz * inv * gv.z + bv.z);
        y.w = f2bf(dw * inv * gv.w + bv.w);
        *(ushort4*)&Y[base] = y;
    }
}

// ---------------- weight transpose + cast ----------------
__global__ __launch_bounds__(256)
void transpose_cast(const float* __restrict__ in, ushort* __restrict__ out,
                    int R, int C, long sIn, long sOut)
{
    __shared__ float tile[32][33];
    in += (long)blockIdx.z * sIn; out += (long)blockIdx.z * sOut;
    const int c0 = blockIdx.x * 32, r0 = blockIdx.y * 32;
    const int tx = threadIdx.x & 31, ty = threadIdx.x >> 5;
    #pragma unroll
    for (int j = 0; j < 4; ++j)
        tile[ty + j * 8][tx] = in[(long)(r0 + ty + j * 8) * C + c0 + tx];
    __syncthreads();
    #pragma unroll
    for (int j = 0; j < 4; ++j)
        out[(long)(c0 + ty + j * 8) * R + r0 + tx] = f2bf(tile[tx][ty + j * 8]);
}

// ---------------- activation transpose: abf [32768,256] -> aT [16][256][2048] ----------------
__global__ __launch_bounds__(256)
void transpose_act(const ushort* __restrict__ in, ushort* __restrict__ out)
{
    __shared__ ushort tile[32][33];
    const int c0 = blockIdx.x * 32, r0 = blockIdx.y * 32;
    const int tx = threadIdx.x & 31, ty = threadIdx.x >> 5;
    #pragma unroll
    for (int j = 0; j < 4; ++j)
        tile[ty + j * 8][tx] = in[(long)(r0 + ty + j * 8) * 256 + c0 + tx];
    __syncthreads();
    const int b = r0 >> 11, nn = r0 & 2047;
    #pragma unroll
    for (int j = 0; j < 4; ++j)
        out[((long)(b * 256 + c0 + ty + j * 8)) * 2048 + nn + tx] = tile[tx][ty + j * 8];
}

// ---------------- bf16 MFMA GEMM, 64x64x32 tile, single-buffer 8KB LDS ----------------
// C[bz] = op( A[bz] @ BT[bz]^T ) — A [M,Kd] bf16, BT [N,Kd] bf16.
// 4 waves in 2x2 quadrants of 32x32 (2x2 frags of 16x16x32 each).
template<int OBF16, int ACT, int HASB>
__global__ __launch_bounds__(256)
void gemm64(const ushort* __restrict__ A, const ushort* __restrict__ BT,
            const float* __restrict__ bias, void* __restrict__ Cout,
            int Kd, int lda, int ldb, int ldc,
            long sA, long sBT, long sC)
{
    __shared__ ushort Als[64 * 32];
    __shared__ ushort Bls[64 * 32];
    const int bz = blockIdx.z;
    const ushort* Ab = A + (long)bz * sA;
    const ushort* Bb = BT + (long)bz * sBT;
    const int m0 = blockIdx.x * 64, n0 = blockIdx.y * 64;
    const int t = threadIdx.x, l = t & 63, w = t >> 6;
    const int wr = w >> 1, wc = w & 1;
    const int fr = l & 15, fq = l >> 4;

    f32x4 acc[2][2];
    #pragma unroll
    for (int m = 0; m < 2; ++m)
        #pragma unroll
        for (int n = 0; n < 2; ++n) acc[m][n] = f32x4{0.f, 0.f, 0.f, 0.f};

    const int srow = t >> 2;            // staging row 0..63
    const int skcol = (t & 3) * 8;      // staging k-offset (ushorts)
    const int dst0 = w * 512;           // wave-uniform LDS base (ushort idx)
    const ushort* Abase = Ab + (long)(m0 + srow) * lda + skcol;
    const ushort* Bbase = Bb + (long)(n0 + srow) * ldb + skcol;

    for (int kk = 0; kk < Kd; kk += 32) {
        __builtin_amdgcn_global_load_lds((const GLOBAL_AS void*)(Abase + kk),
                                         (LDS_AS void*)&Als[dst0], 16, 0, 0);
        __builtin_amdgcn_global_load_lds((const GLOBAL_AS void*)(Bbase + kk),
                                         (LDS_AS void*)&Bls[dst0], 16, 0, 0);
        __syncthreads();                // drains vmcnt(0)
        bf16x8 af[2], bfv[2];
        #pragma unroll
        for (int m = 0; m < 2; ++m)
            af[m] = *(const bf16x8*)&Als[(wr * 32 + m * 16 + fr) * 32 + fq * 8];
        #pragma unroll
        for (int n = 0; n < 2; ++n)
            bfv[n] = *(const bf16x8*)&Bls[(wc * 32 + n * 16 + fr) * 32 + fq * 8];
        #pragma unroll
        for (int m = 0; m < 2; ++m)
            #pragma unroll
            for (int n = 0; n < 2; ++n)
                acc[m][n] = __builtin_amdgcn_mfma_f32_16x16x32_bf16(af[m], bfv[n], acc[m][n], 0, 0, 0);
        __syncthreads();                // protect LDS overwrite
    }

    float bsv[2];
    #pragma unroll
    for (int n = 0; n < 2; ++n) bsv[n] = HASB ? bias[n0 + wc * 32 + n * 16 + fr] : 0.f;
    #pragma unroll
    for (int m = 0; m < 2; ++m) {
        #pragma unroll
        for (int r = 0; r < 4; ++r) {
            const int grow = m0 + wr * 32 + m * 16 + fq * 4 + r;
            const long rowoff = (long)grow * ldc + n0 + wc * 32 + fr;
            #pragma unroll
            for (int n = 0; n < 2; ++n) {
                float v = acc[m][n][r] + bsv[n];
                if (ACT) v = gelu_f(v);
                const long off = rowoff + n * 16;
                if (OBF16) ((ushort*)Cout)[(long)bz * sC + off] = f2bf(v);
                else       ((float*)Cout)[(long)bz * sC + off] = v;
            }
        }
    }
}

// ---------------- fused MFMA attention ----------------
__global__ __launch_bounds__(256)
void attn_mfma(const ushort* __restrict__ Q, const ushort* __restrict__ Kp,
               const ushort* __restrict__ VpT, ushort* __restrict__ O)
{
    __shared__ ushort Qls[64 * 40];
    __shared__ ushort Kls[256 * 40];
    __shared__ ushort Vls[32 * 264];
    __shared__ ushort Pls[64 * 264];
    const int qt = blockIdx.x, h = blockIdx.y, b = blockIdx.z;
    const int n0 = qt * 64;
    const int t = threadIdx.x, w = t >> 6, l = t & 63;
    const int fr = l & 15, fq = l >> 4;

    {
        const int r = t >> 2, c = (t & 3) * 8;
        *(float4*)&Qls[r * 40 + c] =
            *(const float4*)&Q[((long)(b * 2048 + n0 + r)) * 256 + h * 32 + c];
    }
    #pragma unroll
    for (int it = 0; it < 4; ++it) {
        const int r = (t >> 2) + it * 64, c = (t & 3) * 8;
        *(float4*)&Kls[r * 40 + c] =
            *(const float4*)&Kp[((long)(b * 256 + r)) * 256 + h * 32 + c];
    }
    {
        const int r = t >> 3, c0 = (t & 7) * 32;
        const ushort* src = VpT + ((long)(b * 256 + h * 32 + r)) * 256 + c0;
        #pragma unroll
        for (int j = 0; j < 4; ++j)
            *(float4*)&Vls[r * 264 + c0 + j * 8] = *(const float4*)(src + j * 8);
    }
    __syncthreads();

    const bf16x8 aq = *(const bf16x8*)&Qls[(w * 16 + fr) * 40 + fq * 8];
    f32x4 s[16];
    #pragma unroll
    for (int n = 0; n < 16; ++n) {
        const bf16x8 bk = *(const bf16x8*)&Kls[(n * 16 + fr) * 40 + fq * 8];
        s[n] = __builtin_amdgcn_mfma_f32_16x16x32_bf16(aq, bk, f32x4{0.f,0.f,0.f,0.f}, 0, 0, 0);
    }
    const float scale = 0.17677669529663687f;
    float mx[4] = {-1e30f, -1e30f, -1e30f, -1e30f};
    #pragma unroll
    for (int n = 0; n < 16; ++n)
        #pragma unroll
        for (int r = 0; r < 4; ++r) { s[n][r] *= scale; mx[r] = fmaxf(mx[r], s[n][r]); }
    #pragma unroll
    for (int m = 1; m <= 8; m <<= 1)
        #pragma unroll
        for (int r = 0; r < 4; ++r) mx[r] = fmaxf(mx[r], __shfl_xor(mx[r], m));
    float sm[4] = {0.f, 0.f, 0.f, 0.f};
    #pragma unroll
    for (int n = 0; n < 16; ++n)
        #pragma unroll
        for (int r = 0; r < 4; ++r) {
            const float e = __expf(s[n][r] - mx[r]);
            s[n][r] = e; sm[r] += e;
        }
    #pragma unroll
    for (int m = 1; m <= 8; m <<= 1)
        #pragma unroll
        for (int r = 0; r < 4; ++r) sm[r] += __shfl_xor(sm[r], m);
    #pragma unroll
    for (int n = 0; n < 16; ++n)
        #pragma unroll
        for (int r = 0; r < 4; ++r)
            Pls[(w * 16 + fq * 4 + r) * 264 + n * 16 + fr] = f2bf(s[n][r]);
    __syncthreads();

    f32x4 o[2] = {f32x4{0.f,0.f,0.f,0.f}, f32x4{0.f,0.f,0.f,0.f}};
    #pragma unroll
    for (int kk = 0; kk < 8; ++kk) {
        const bf16x8 ap = *(const bf16x8*)&Pls[(w * 16 + fr) * 264 + kk * 32 + fq * 8];
        #pragma unroll
        for (int n = 0; n < 2; ++n) {
            const bf16x8 bv = *(const bf16x8*)&Vls[(n * 16 + fr) * 264 + kk * 32 + fq * 8];
            o[n] = __builtin_amdgcn_mfma_f32_16x16x32_bf16(ap, bv, o[n], 0, 0, 0);
        }
    }
    float inv[4];
    #pragma unroll
    for (int r = 0; r < 4; ++r) inv[r] = 1.0f / sm[r];
    #pragma unroll
    for (int n = 0; n < 2; ++n)
        #pragma unroll
        for (int r = 0; r < 4; ++r)
            O[((long)(b * 2048 + n0 + w * 16 + fq * 4 + r)) * 256 + h * 32 + n * 16 + fr] =
                f2bf(o[n][r] * inv[r]);
}

// ---------------- final head ----------------
__global__ __launch_bounds__(256)
void out_kernel(const float* __restrict__ H, const float* __restrict__ Wout,
                const float* __restrict__ bout, float* __restrict__ out)
{
    const int row = blockIdx.x * 4 + (threadIdx.x >> 6);
    const int lane = threadIdx.x & 63;
    float4 hv = *(const float4*)&H[(long)row * 256 + lane * 4];
    float4 wv = *(const float4*)&Wout[lane * 4];
    float s = hv.x * wv.x + hv.y * wv.y + hv.z * wv.z + hv.w * wv.w;
    #pragma unroll
    for (int m = 32; m >= 1; m >>= 1) s += __shfl_xor(s, m);
    if (lane == 0) out[row] = s + bout[0];
}

extern "C" void kernel_launch(void* const* d_in, const int* in_sizes, int n_in,
                              void* d_out, int out_size, void* d_ws, size_t ws_size,
                              hipStream_t stream)
{
    const float* x    = (const float*)d_in[0];
    const float* Wemb = (const float*)d_in[1];
    const float* bemb = (const float*)d_in[2];
    const float* pos  = (const float*)d_in[3];
    const float* ln0g = (const float*)d_in[4];
    const float* ln0b = (const float*)d_in[5];
    const float* ln1g = (const float*)d_in[6];
    const float* ln1b = (const float*)d_in[7];
    const float* Wq   = (const float*)d_in[8];
    const float* Wk   = (const float*)d_in[9];
    const float* Wv   = (const float*)d_in[10];
    const float* Ek   = (const float*)d_in[11];
    const float* Ev   = (const float*)d_in[12];
    const float* Wo   = (const float*)d_in[13];
    const float* bo   = (const float*)d_in[14];
    const float* ln2g = (const float*)d_in[15];
    const float* ln2b = (const float*)d_in[16];
    const float* W1   = (const float*)d_in[17];
    const float* b1   = (const float*)d_in[18];
    const float* W2   = (const float*)d_in[19];
    const float* b2   = (const float*)d_in[20];
    const float* Wout = (const float*)d_in[21];
    const float* bout = (const float*)d_in[22];

    // Workspace layout (lifetime-overlapped; peak ~132 MB):
    //   h    f32 [32768,256]      @ 0
    //   abf  bf16 [32768,256]     @ 33,554,432  (LN out / attn out / W2-delta)
    //   aT   bf16 [16][256][2048] @ 50,331,648
    //   kp/vpT/apkv | obuf        @ 67,108,864  (obuf bf16 = Wo delta, after attn)
    //   qbf  bf16 [32768,256]     @ 100,663,296
    //   hid  bf16 [32768,1024]    @ 50,331,648  (overlaps aT..qbf; FFN phase only)
    //   WT   weights bf16         @ 117,440,512
    char* ws = (char*)d_ws;
    float*  h    = (float*)(ws + 0);
    ushort* abf  = (ushort*)(ws + 33554432L);
    ushort* aT   = (ushort*)(ws + 50331648L);
    ushort* kp   = (ushort*)(ws + 67108864L);
    ushort* vpT  = (ushort*)(ws + 69206016L);
    ushort* apkv = (ushort*)(ws + 71303168L);
    ushort* obuf = (ushort*)(ws + 67108864L);
    ushort* qbf  = (ushort*)(ws + 100663296L);
    ushort* hid  = (ushort*)(ws + 50331648L);
    ushort* WT   = (ushort*)(ws + 117440512L);
    ushort* WqT  = WT;
    ushort* WkT  = WT + 262144;
    ushort* WvT  = WT + 524288;
    ushort* WoT  = WT + 786432;
    ushort* W1T  = WT + 1048576;
    ushort* W2T  = WT + 2097152;
    ushort* EkvT = WT + 3145728;
    float* outp = (float*)d_out;

    transpose_cast<<<dim3(8, 8, 4), 256, 0, stream>>>(Wq, WqT, 256, 256, 65536, 65536);
    transpose_cast<<<dim3(8, 8, 4), 256, 0, stream>>>(Wk, WkT, 256, 256, 65536, 65536);
    transpose_cast<<<dim3(8, 8, 4), 256, 0, stream>>>(Wv, WvT, 256, 256, 65536, 65536);
    transpose_cast<<<dim3(8, 8, 4), 256, 0, stream>>>(Wo, WoT, 256, 256, 65536, 65536);
    transpose_cast<<<dim3(32, 8, 4), 256, 0, stream>>>(W1, W1T, 256, 1024, 262144, 262144);
    transpose_cast<<<dim3(8, 32, 4), 256, 0, stream>>>(W2, W2T, 1024, 256, 262144, 262144);
    transpose_cast<<<dim3(8, 64, 4), 256, 0, stream>>>(Ek, EkvT, 2048, 256, 524288, 1048576);
    transpose_cast<<<dim3(8, 64, 4), 256, 0, stream>>>(Ev, EkvT + 524288, 2048, 256, 524288, 1048576);

    embed_ln2<<<8192, 256, 0, stream>>>(x, Wemb, bemb, pos, ln0g, ln0b, h);
    ln_kernel<<<8192, 256, 0, stream>>>(h, ln1g, ln1b, abf);
    transpose_act<<<dim3(8, 1024), 256, 0, stream>>>(abf, aT);

    for (int i = 0; i < 4; ++i) {
        const ushort* WqT_i = WqT + i * 65536;
        const ushort* WkT_i = WkT + i * 65536;
        const ushort* WvT_i = WvT + i * 65536;
        const ushort* WoT_i = WoT + i * 65536;
        const ushort* W1T_i = W1T + i * 262144;
        const ushort* W2T_i = W2T + i * 262144;
        const ushort* EkvT_i = EkvT + (long)i * 1048576;

        // q = a @ Wq (bf16) — 2048 blocks
        gemm64<1,0,0><<<dim3(512, 4, 1), 256, 0, stream>>>(abf, WqT_i, nullptr, qbf,
            256, 256, 256, 256, 0, 0, 0);
        // apkv[b] = [Ek^T; Ev^T] @ a[b] (bf16) — 512 blocks, 64 iters
        gemm64<1,0,0><<<dim3(8, 4, 16), 256, 0, stream>>>(EkvT_i, aT, nullptr, apkv,
            2048, 2048, 2048, 256, 0, 524288, 131072);
        // kp[b] = apk[b] @ Wk (bf16, row=key)
        gemm64<1,0,0><<<dim3(4, 4, 16), 256, 0, stream>>>(apkv, WkT_i, nullptr, kp,
            256, 256, 256, 256, 131072, 0, 65536);
        // vpT[b] = Wv^T @ apv[b]^T (bf16, row=d, col=key)
        gemm64<1,0,0><<<dim3(4, 4, 16), 256, 0, stream>>>(WvT_i, apkv + 65536, nullptr, vpT,
            256, 256, 256, 256, 0, 131072, 65536);
        // fused MFMA attention -> abf (bf16); kp/vpT/apkv dead afterwards
        attn_mfma<<<dim3(32, 8, 16), 256, 0, stream>>>(qbf, kp, vpT, abf);
        // delta_o = attnout @ Wo (bf16 streaming) — 2048 blocks
        gemm64<1,0,0><<<dim3(512, 4, 1), 256, 0, stream>>>(abf, WoT_i, nullptr, obuf,
            256, 256, 256, 256, 0, 0, 0);
        // h += delta_o + bo ; abf = LN2(h)
        add_ln<1><<<8192, 256, 0, stream>>>(h, obuf, bo + i * 256,
            ln2g + i * 256, ln2b + i * 256, abf);
        // hid = gelu(a @ W1 + b1) (bf16) — single N=1024 dispatch, 8192 blocks
        gemm64<1,1,1><<<dim3(512, 16, 1), 256, 0, stream>>>(abf, W1T_i,
            b1 + (long)i * 1024, hid, 256, 256, 256, 1024, 0, 0, 0);
        // delta_2 = hid @ W2 (bf16 into abf; A=hid dead after) — 2048 blocks, 32 iters
        gemm64<1,0,0><<<dim3(512, 4, 1), 256, 0, stream>>>(hid, W2T_i, nullptr, abf,
            1024, 1024, 1024, 256, 0, 0, 0);
        if (i < 3) {
            add_ln<1><<<8192, 256, 0, stream>>>(h, abf, b2 + i * 256,
                ln1g + (i + 1) * 256, ln1b + (i + 1) * 256, abf);
            transpose_act<<<dim3(8, 1024), 256, 0, stream>>>(abf, aT);
        } else {
            add_ln<0><<<8192, 256, 0, stream>>>(h, abf, b2 + i * 256,
                nullptr, nullptr, nullptr);
        }
    }
    out_kernel<<<8192, 256, 0, stream>>>(h, Wout, bout, outp);
}

// Round 9
// 941.678 us; speedup vs baseline: 1.1355x; 1.0322x over previous
//
#include <hip/hip_runtime.h>
#include <hip/hip_bf16.h>

// Model dims: B=16, N=2048, F=40, D=256, H=8, K=256, L=4, DH=32
// fp32 inputs/outputs; bf16 MFMA GEMMs + attention; fp32 residual stream.
// GEMM: 64x64x32 tiles, 8 blocks/CU. Residual adds fused into GEMM epilogues (f32 RMW).
// Attention: swapped QK^T (S^T per-lane) + in-register P redistribution, 37KB LDS.

typedef short bf16x8 __attribute__((ext_vector_type(8)));
typedef float f32x4 __attribute__((ext_vector_type(4)));
typedef unsigned int u32x4 __attribute__((ext_vector_type(4)));

#define GLOBAL_AS __attribute__((address_space(1)))
#define LDS_AS __attribute__((address_space(3)))

static __device__ __forceinline__ float gelu_f(float v) {
    return 0.5f * v * (1.0f + erff(v * 0.70710678118654752f));
}
static __device__ __forceinline__ ushort f2bf(float x) {
    __hip_bfloat16 h = __float2bfloat16(x);
    return __builtin_bit_cast(ushort, h);
}

// ---------------- embed + pos + LN0: wave-per-row ----------------
__global__ __launch_bounds__(256)
void embed_ln2(const float* __restrict__ x, const float* __restrict__ Wemb,
               const float* __restrict__ bemb, const float* __restrict__ pos,
               const float* __restrict__ g0, const float* __restrict__ b0,
               float* __restrict__ H)
{
    const int t = threadIdx.x, w = t >> 6, l = t & 63;
    const long row = (long)blockIdx.x * 4 + w;
    const int n = (int)(row & 2047);
    const float xl = (l < 40) ? x[row * 40 + l] : 0.f;
    float4 acc = *(const float4*)&bemb[l * 4];
    const float4 pv = *(const float4*)&pos[(long)n * 256 + l * 4];
    acc.x += pv.x; acc.y += pv.y; acc.z += pv.z; acc.w += pv.w;
    #pragma unroll 8
    for (int f = 0; f < 40; ++f) {
        const float xf = __shfl(xl, f);
        const float4 wv = *(const float4*)&Wemb[f * 256 + l * 4];
        acc.x += xf * wv.x; acc.y += xf * wv.y; acc.z += xf * wv.z; acc.w += xf * wv.w;
    }
    float s = acc.x + acc.y + acc.z + acc.w;
    #pragma unroll
    for (int m = 32; m >= 1; m >>= 1) s += __shfl_xor(s, m);
    const float mean = s * (1.0f / 256.0f);
    const float dx = acc.x - mean, dy = acc.y - mean, dz = acc.z - mean, dw = acc.w - mean;
    float q = dx * dx + dy * dy + dz * dz + dw * dw;
    #pragma unroll
    for (int m = 32; m >= 1; m >>= 1) q += __shfl_xor(q, m);
    const float inv = rsqrtf(q * (1.0f / 256.0f) + 1e-5f);
    const float4 gv = *(const float4*)&g0[l * 4];
    const float4 bv = *(const float4*)&b0[l * 4];
    float4 y;
    y.x = dx * inv * gv.x + bv.x;
    y.y = dy * inv * gv.y + bv.y;
    y.z = dz * inv * gv.z + bv.z;
    y.w = dw * inv * gv.w + bv.w;
    *(float4*)&H[row * 256 + l * 4] = y;
}

// ---------------- LayerNorm fp32 -> bf16 ----------------
__global__ __launch_bounds__(256)
void ln_kernel(const float* __restrict__ X, const float* __restrict__ g,
               const float* __restrict__ b, ushort* __restrict__ Y)
{
    const int row = blockIdx.x * 4 + (threadIdx.x >> 6);
    const int lane = threadIdx.x & 63;
    const long base = (long)row * 256 + lane * 4;
    float4 xv = *(const float4*)&X[base];
    float s = xv.x + xv.y + xv.z + xv.w;
    #pragma unroll
    for (int m = 32; m >= 1; m >>= 1) s += __shfl_xor(s, m);
    const float mean = s * (1.0f / 256.0f);
    const float dx = xv.x - mean, dy = xv.y - mean, dz = xv.z - mean, dw = xv.w - mean;
    float q = dx * dx + dy * dy + dz * dz + dw * dw;
    #pragma unroll
    for (int m = 32; m >= 1; m >>= 1) q += __shfl_xor(q, m);
    const float inv = rsqrtf(q * (1.0f / 256.0f) + 1e-5f);
    const float4 gv = *(const float4*)&g[lane * 4];
    const float4 bv = *(const float4*)&b[lane * 4];
    ushort4 y;
    y.x = f2bf(dx * inv * gv.x + bv.x);
    y.y = f2bf(dy * inv * gv.y + bv.y);
    y.z = f2bf(dz * inv * gv.z + bv.z);
    y.w = f2bf(dw * inv * gv.w + bv.w);
    *(ushort4*)&Y[base] = y;
}

// ---------------- weight transpose + cast ----------------
__global__ __launch_bounds__(256)
void transpose_cast(const float* __restrict__ in, ushort* __restrict__ out,
                    int R, int C, long sIn, long sOut)
{
    __shared__ float tile[32][33];
    in += (long)blockIdx.z * sIn; out += (long)blockIdx.z * sOut;
    const int c0 = blockIdx.x * 32, r0 = blockIdx.y * 32;
    const int tx = threadIdx.x & 31, ty = threadIdx.x >> 5;
    #pragma unroll
    for (int j = 0; j < 4; ++j)
        tile[ty + j * 8][tx] = in[(long)(r0 + ty + j * 8) * C + c0 + tx];
    __syncthreads();
    #pragma unroll
    for (int j = 0; j < 4; ++j)
        out[(long)(c0 + ty + j * 8) * R + r0 + tx] = f2bf(tile[tx][ty + j * 8]);
}

// ---------------- activation transpose: abf [32768,256] -> aT [16][256][2048] ----------------
__global__ __launch_bounds__(256)
void transpose_act(const ushort* __restrict__ in, ushort* __restrict__ out)
{
    __shared__ ushort tile[32][33];
    const int c0 = blockIdx.x * 32, r0 = blockIdx.y * 32;
    const int tx = threadIdx.x & 31, ty = threadIdx.x >> 5;
    #pragma unroll
    for (int j = 0; j < 4; ++j)
        tile[ty + j * 8][tx] = in[(long)(r0 + ty + j * 8) * 256 + c0 + tx];
    __syncthreads();
    const int b = r0 >> 11, nn = r0 & 2047;
    #pragma unroll
    for (int j = 0; j < 4; ++j)
        out[((long)(b * 256 + c0 + ty + j * 8)) * 2048 + nn + tx] = tile[tx][ty + j * 8];
}

// ---------------- bf16 MFMA GEMM, 64x64x32 tile, single-buffer 8KB LDS ----------------
// C[bz] = op( A[bz] @ BT[bz]^T ) — A [M,Kd] bf16, BT [N,Kd] bf16.
// ACCF=1: Cout is f32 and epilogue does h += acc + bias (RMW).
template<int OBF16, int ACT, int HASB, int ACCF>
__global__ __launch_bounds__(256)
void gemm64(const ushort* __restrict__ A, const ushort* __restrict__ BT,
            const float* __restrict__ bias, void* __restrict__ Cout,
            int Kd, int lda, int ldb, int ldc,
            long sA, long sBT, long sC)
{
    __shared__ ushort Als[64 * 32];
    __shared__ ushort Bls[64 * 32];
    const int bz = blockIdx.z;
    const ushort* Ab = A + (long)bz * sA;
    const ushort* Bb = BT + (long)bz * sBT;
    const int m0 = blockIdx.x * 64, n0 = blockIdx.y * 64;
    const int t = threadIdx.x, l = t & 63, w = t >> 6;
    const int wr = w >> 1, wc = w & 1;
    const int fr = l & 15, fq = l >> 4;

    f32x4 acc[2][2];
    #pragma unroll
    for (int m = 0; m < 2; ++m)
        #pragma unroll
        for (int n = 0; n < 2; ++n) acc[m][n] = f32x4{0.f, 0.f, 0.f, 0.f};

    const int srow = t >> 2;
    const int skcol = (t & 3) * 8;
    const int dst0 = w * 512;
    const ushort* Abase = Ab + (long)(m0 + srow) * lda + skcol;
    const ushort* Bbase = Bb + (long)(n0 + srow) * ldb + skcol;

    for (int kk = 0; kk < Kd; kk += 32) {
        __builtin_amdgcn_global_load_lds((const GLOBAL_AS void*)(Abase + kk),
                                         (LDS_AS void*)&Als[dst0], 16, 0, 0);
        __builtin_amdgcn_global_load_lds((const GLOBAL_AS void*)(Bbase + kk),
                                         (LDS_AS void*)&Bls[dst0], 16, 0, 0);
        __syncthreads();
        bf16x8 af[2], bfv[2];
        #pragma unroll
        for (int m = 0; m < 2; ++m)
            af[m] = *(const bf16x8*)&Als[(wr * 32 + m * 16 + fr) * 32 + fq * 8];
        #pragma unroll
        for (int n = 0; n < 2; ++n)
            bfv[n] = *(const bf16x8*)&Bls[(wc * 32 + n * 16 + fr) * 32 + fq * 8];
        #pragma unroll
        for (int m = 0; m < 2; ++m)
            #pragma unroll
            for (int n = 0; n < 2; ++n)
                acc[m][n] = __builtin_amdgcn_mfma_f32_16x16x32_bf16(af[m], bfv[n], acc[m][n], 0, 0, 0);
        __syncthreads();
    }

    float bsv[2];
    #pragma unroll
    for (int n = 0; n < 2; ++n) bsv[n] = HASB ? bias[n0 + wc * 32 + n * 16 + fr] : 0.f;
    #pragma unroll
    for (int m = 0; m < 2; ++m) {
        #pragma unroll
        for (int r = 0; r < 4; ++r) {
            const int grow = m0 + wr * 32 + m * 16 + fq * 4 + r;
            const long rowoff = (long)grow * ldc + n0 + wc * 32 + fr;
            #pragma unroll
            for (int n = 0; n < 2; ++n) {
                float v = acc[m][n][r] + bsv[n];
                if (ACT) v = gelu_f(v);
                const long off = rowoff + n * 16;
                if (OBF16) {
                    ((ushort*)Cout)[(long)bz * sC + off] = f2bf(v);
                } else {
                    float* Cp = (float*)Cout + (long)bz * sC;
                    if (ACCF) v += Cp[off];
                    Cp[off] = v;
                }
            }
        }
    }
}

// ---------------- fused MFMA attention, swapped-operand, P in registers ----------------
// grid (N/64, H, B), 256 threads (4 waves x 16 q-rows).
// Q: [B*N,256] bf16 (head slice), Kp: [B][256][256] bf16 (row=key),
// VpT: [B][256][256] bf16 (row=d, col=key), O: [B*N,256] bf16.
__global__ __launch_bounds__(256)
void attn_mfma2(const ushort* __restrict__ Q, const ushort* __restrict__ Kp,
                const ushort* __restrict__ VpT, ushort* __restrict__ O)
{
    __shared__ ushort Kls[256 * 40];   // 20.5 KB
    __shared__ ushort Vls[32 * 264];   // 16.9 KB
    const int qt = blockIdx.x, h = blockIdx.y, b = blockIdx.z;
    const int n0 = qt * 64;
    const int t = threadIdx.x, w = t >> 6, l = t & 63;
    const int fr = l & 15, fq = l >> 4;

    // stage K (256 keys x 32 d)
    #pragma unroll
    for (int it = 0; it < 4; ++it) {
        const int r = (t >> 2) + it * 64, c = (t & 3) * 8;
        *(float4*)&Kls[r * 40 + c] =
            *(const float4*)&Kp[((long)(b * 256 + r)) * 256 + h * 32 + c];
    }
    // stage V^T (32 d x 256 keys)
    {
        const int r = t >> 3, c0 = (t & 7) * 32;
        const ushort* src = VpT + ((long)(b * 256 + h * 32 + r)) * 256 + c0;
        #pragma unroll
        for (int j = 0; j < 4; ++j)
            *(float4*)&Vls[r * 264 + c0 + j * 8] = *(const float4*)(src + j * 8);
    }
    // Q fragment direct from global (B-operand: lane holds Q[q=fr][d=fq*8..+7])
    const bf16x8 bq = *(const bf16x8*)
        &Q[((long)(b * 2048 + n0 + w * 16 + fr)) * 256 + h * 32 + fq * 8];
    __syncthreads();

    // S^T = K @ Q^T : 16 frags over keys. Lane holds col q=fr, rows key=16n+fq*4+r.
    f32x4 s[16];
    #pragma unroll
    for (int n = 0; n < 16; ++n) {
        const bf16x8 ak = *(const bf16x8*)&Kls[(n * 16 + fr) * 40 + fq * 8];
        s[n] = __builtin_amdgcn_mfma_f32_16x16x32_bf16(ak, bq, f32x4{0.f,0.f,0.f,0.f}, 0, 0, 0);
    }
    // softmax for q=fr: 64 lane-local values + cross-fq reduce (xor 16, 32)
    const float scale = 0.17677669529663687f;   // 1/sqrt(32)
    float mx = -1e30f;
    #pragma unroll
    for (int n = 0; n < 16; ++n)
        #pragma unroll
        for (int r = 0; r < 4; ++r) { s[n][r] *= scale; mx = fmaxf(mx, s[n][r]); }
    mx = fmaxf(mx, __shfl_xor(mx, 16));
    mx = fmaxf(mx, __shfl_xor(mx, 32));
    float sm = 0.f;
    unsigned int p[16][2];   // packed bf16 pairs: p[n][rr] = (bf(e[2rr+1])<<16)|bf(e[2rr])
    #pragma unroll
    for (int n = 0; n < 16; ++n) {
        float e0 = __expf(s[n][0] - mx), e1 = __expf(s[n][1] - mx);
        float e2 = __expf(s[n][2] - mx), e3 = __expf(s[n][3] - mx);
        sm += (e0 + e1) + (e2 + e3);
        p[n][0] = ((unsigned int)f2bf(e1) << 16) | f2bf(e0);
        p[n][1] = ((unsigned int)f2bf(e3) << 16) | f2bf(e2);
    }
    sm += __shfl_xor(sm, 16);
    sm += __shfl_xor(sm, 32);

    // PV: O^T = V^T @ P^T. Build P^T B-frags by lane redistribution:
    // word wd of breg (keys 32kk+8fq+2wd..+1) comes from lane fr+16*(2*(fq&1)+(wd>>1)),
    // frag n=2kk+(fq>>1), pair rr=wd&1.
    const int fqa = fq & 1, fqb = fq >> 1;
    f32x4 o[2] = {f32x4{0.f,0.f,0.f,0.f}, f32x4{0.f,0.f,0.f,0.f}};
    #pragma unroll
    for (int kk = 0; kk < 8; ++kk) {
        u32x4 bw;
        #pragma unroll
        for (int wd = 0; wd < 4; ++wd) {
            const int srcl = fr + ((2 * fqa + (wd >> 1)) << 4);
            const unsigned int v0 = __shfl((int)p[2 * kk][wd & 1], srcl);
            const unsigned int v1 = __shfl((int)p[2 * kk + 1][wd & 1], srcl);
            bw[wd] = fqb ? v1 : v0;
        }
        const bf16x8 breg = __builtin_bit_cast(bf16x8, bw);
        #pragma unroll
        for (int nd = 0; nd < 2; ++nd) {
            const bf16x8 av = *(const bf16x8*)&Vls[(nd * 16 + fr) * 264 + kk * 32 + fq * 8];
            o[nd] = __builtin_amdgcn_mfma_f32_16x16x32_bf16(av, breg, o[nd], 0, 0, 0);
        }
    }
    // O^T frag: row d = nd*16 + fq*4 + r, col q = fr -> per lane: one row, 2x ushort4.
    const float inv = 1.0f / sm;
    const long rowbase = ((long)(b * 2048 + n0 + w * 16 + fr)) * 256 + h * 32;
    #pragma unroll
    for (int nd = 0; nd < 2; ++nd) {
        ushort4 y;
        y.x = f2bf(o[nd][0] * inv); y.y = f2bf(o[nd][1] * inv);
        y.z = f2bf(o[nd][2] * inv); y.w = f2bf(o[nd][3] * inv);
        *(ushort4*)&O[rowbase + nd * 16 + fq * 4] = y;
    }
}

// ---------------- final head ----------------
__global__ __launch_bounds__(256)
void out_kernel(const float* __restrict__ H, const float* __restrict__ Wout,
                const float* __restrict__ bout, float* __restrict__ out)
{
    const int row = blockIdx.x * 4 + (threadIdx.x >> 6);
    const int lane = threadIdx.x & 63;
    float4 hv = *(const float4*)&H[(long)row * 256 + lane * 4];
    float4 wv = *(const float4*)&Wout[lane * 4];
    float s = hv.x * wv.x + hv.y * wv.y + hv.z * wv.z + hv.w * wv.w;
    #pragma unroll
    for (int m = 32; m >= 1; m >>= 1) s += __shfl_xor(s, m);
    if (lane == 0) out[row] = s + bout[0];
}

extern "C" void kernel_launch(void* const* d_in, const int* in_sizes, int n_in,
                              void* d_out, int out_size, void* d_ws, size_t ws_size,
                              hipStream_t stream)
{
    const float* x    = (const float*)d_in[0];
    const float* Wemb = (const float*)d_in[1];
    const float* bemb = (const float*)d_in[2];
    const float* pos  = (const float*)d_in[3];
    const float* ln0g = (const float*)d_in[4];
    const float* ln0b = (const float*)d_in[5];
    const float* ln1g = (const float*)d_in[6];
    const float* ln1b = (const float*)d_in[7];
    const float* Wq   = (const float*)d_in[8];
    const float* Wk   = (const float*)d_in[9];
    const float* Wv   = (const float*)d_in[10];
    const float* Ek   = (const float*)d_in[11];
    const float* Ev   = (const float*)d_in[12];
    const float* Wo   = (const float*)d_in[13];
    const float* bo   = (const float*)d_in[14];
    const float* ln2g = (const float*)d_in[15];
    const float* ln2b = (const float*)d_in[16];
    const float* W1   = (const float*)d_in[17];
    const float* b1   = (const float*)d_in[18];
    const float* W2   = (const float*)d_in[19];
    const float* b2   = (const float*)d_in[20];
    const float* Wout = (const float*)d_in[21];
    const float* bout = (const float*)d_in[22];

    // Workspace (lifetime-overlapped; peak ~132 MB):
    //   h    f32 [32768,256]      @ 0
    //   abf  bf16 [32768,256]     @ 33,554,432  (LN out / attn out)
    //   aT   bf16 [16][256][2048] @ 50,331,648
    //   kp/vpT/apkv               @ 67,108,864
    //   qbf  bf16 [32768,256]     @ 100,663,296
    //   hid  bf16 [32768,1024]    @ 50,331,648  (overlaps aT..qbf; FFN phase only)
    //   WT   weights bf16         @ 117,440,512
    char* ws = (char*)d_ws;
    float*  h    = (float*)(ws + 0);
    ushort* abf  = (ushort*)(ws + 33554432L);
    ushort* aT   = (ushort*)(ws + 50331648L);
    ushort* kp   = (ushort*)(ws + 67108864L);
    ushort* vpT  = (ushort*)(ws + 69206016L);
    ushort* apkv = (ushort*)(ws + 71303168L);
    ushort* qbf  = (ushort*)(ws + 100663296L);
    ushort* hid  = (ushort*)(ws + 50331648L);
    ushort* WT   = (ushort*)(ws + 117440512L);
    ushort* WqT  = WT;
    ushort* WkT  = WT + 262144;
    ushort* WvT  = WT + 524288;
    ushort* WoT  = WT + 786432;
    ushort* W1T  = WT + 1048576;
    ushort* W2T  = WT + 2097152;
    ushort* EkvT = WT + 3145728;
    float* outp = (float*)d_out;

    transpose_cast<<<dim3(8, 8, 4), 256, 0, stream>>>(Wq, WqT, 256, 256, 65536, 65536);
    transpose_cast<<<dim3(8, 8, 4), 256, 0, stream>>>(Wk, WkT, 256, 256, 65536, 65536);
    transpose_cast<<<dim3(8, 8, 4), 256, 0, stream>>>(Wv, WvT, 256, 256, 65536, 65536);
    transpose_cast<<<dim3(8, 8, 4), 256, 0, stream>>>(Wo, WoT, 256, 256, 65536, 65536);
    transpose_cast<<<dim3(32, 8, 4), 256, 0, stream>>>(W1, W1T, 256, 1024, 262144, 262144);
    transpose_cast<<<dim3(8, 32, 4), 256, 0, stream>>>(W2, W2T, 1024, 256, 262144, 262144);
    transpose_cast<<<dim3(8, 64, 4), 256, 0, stream>>>(Ek, EkvT, 2048, 256, 524288, 1048576);
    transpose_cast<<<dim3(8, 64, 4), 256, 0, stream>>>(Ev, EkvT + 524288, 2048, 256, 524288, 1048576);

    embed_ln2<<<8192, 256, 0, stream>>>(x, Wemb, bemb, pos, ln0g, ln0b, h);
    ln_kernel<<<8192, 256, 0, stream>>>(h, ln1g, ln1b, abf);
    transpose_act<<<dim3(8, 1024), 256, 0, stream>>>(abf, aT);

    for (int i = 0; i < 4; ++i) {
        const ushort* WqT_i = WqT + i * 65536;
        const ushort* WkT_i = WkT + i * 65536;
        const ushort* WvT_i = WvT + i * 65536;
        const ushort* WoT_i = WoT + i * 65536;
        const ushort* W1T_i = W1T + i * 262144;
        const ushort* W2T_i = W2T + i * 262144;
        const ushort* EkvT_i = EkvT + (long)i * 1048576;

        // q = a @ Wq (bf16) — 2048 blocks
        gemm64<1,0,0,0><<<dim3(512, 4, 1), 256, 0, stream>>>(abf, WqT_i, nullptr, qbf,
            256, 256, 256, 256, 0, 0, 0);
        // apkv[b] = [Ek^T; Ev^T] @ a[b] (bf16) — 512 blocks, 64 iters
        gemm64<1,0,0,0><<<dim3(8, 4, 16), 256, 0, stream>>>(EkvT_i, aT, nullptr, apkv,
            2048, 2048, 2048, 256, 0, 524288, 131072);
        // kp[b] = apk[b] @ Wk (bf16, row=key)
        gemm64<1,0,0,0><<<dim3(4, 4, 16), 256, 0, stream>>>(apkv, WkT_i, nullptr, kp,
            256, 256, 256, 256, 131072, 0, 65536);
        // vpT[b] = Wv^T @ apv[b]^T (bf16, row=d, col=key)
        gemm64<1,0,0,0><<<dim3(4, 4, 16), 256, 0, stream>>>(WvT_i, apkv + 65536, nullptr, vpT,
            256, 256, 256, 256, 0, 131072, 65536);
        // fused MFMA attention -> abf (bf16)
        attn_mfma2<<<dim3(32, 8, 16), 256, 0, stream>>>(qbf, kp, vpT, abf);
        // h += attnout @ Wo + bo (f32 RMW epilogue)
        gemm64<0,0,1,1><<<dim3(512, 4, 1), 256, 0, stream>>>(abf, WoT_i, bo + i * 256, h,
            256, 256, 256, 256, 0, 0, 0);
        // abf = LN2(h)
        ln_kernel<<<8192, 256, 0, stream>>>(h, ln2g + i * 256, ln2b + i * 256, abf);
        // hid = gelu(a @ W1 + b1) (bf16) — 8192 blocks
        gemm64<1,1,1,0><<<dim3(512, 16, 1), 256, 0, stream>>>(abf, W1T_i,
            b1 + (long)i * 1024, hid, 256, 256, 256, 1024, 0, 0, 0);
        // h += hid @ W2 + b2 (f32 RMW epilogue) — 2048 blocks, 32 iters
        gemm64<0,0,1,1><<<dim3(512, 4, 1), 256, 0, stream>>>(hid, W2T_i, b2 + i * 256, h,
            1024, 1024, 1024, 256, 0, 0, 0);
        if (i < 3) {
            ln_kernel<<<8192, 256, 0, stream>>>(h, ln1g + (i + 1) * 256,
                ln1b + (i + 1) * 256, abf);
            transpose_act<<<dim3(8, 1024), 256, 0, stream>>>(abf, aT);
        }
    }
    out_kernel<<<8192, 256, 0, stream>>>(h, Wout, bout, outp);
}

// Round 10
// 937.227 us; speedup vs baseline: 1.1409x; 1.0047x over previous
//
#include <hip/hip_runtime.h>
#include <hip/hip_bf16.h>

// Model dims: B=16, N=2048, F=40, D=256, H=8, K=256, L=4, DH=32
// fp32 inputs/outputs; bf16 MFMA GEMMs + attention; fp32 residual stream.
// GEMM: 64x64x32 tiles, 8 blocks/CU; residual adds fused in epilogues (f32 RMW).
// Attention: swapped QK^T + in-register P redistribution, 37KB LDS.
// Embed: 8 rows/wave amortizes Wemb L1 traffic; GELU via exp-based tanh approx.

typedef short bf16x8 __attribute__((ext_vector_type(8)));
typedef float f32x4 __attribute__((ext_vector_type(4)));
typedef unsigned int u32x4 __attribute__((ext_vector_type(4)));

#define GLOBAL_AS __attribute__((address_space(1)))
#define LDS_AS __attribute__((address_space(3)))

static __device__ __forceinline__ float gelu_f(float v) {
    // tanh-form GELU: 0.5*v*(1+tanh(0.79788456*(v+0.044715*v^3)))
    // tanh(u) = 1 - 2/(exp(2u)+1); |err| vs erf-GELU < 2e-4 on relevant range.
    const float u2 = v * (0.7978845608028654f + 0.03567740814183427f * v * v);
    const float t = 1.0f - 2.0f / (__expf(2.0f * u2) + 1.0f);
    return 0.5f * v * (1.0f + t);
}
static __device__ __forceinline__ ushort f2bf(float x) {
    __hip_bfloat16 h = __float2bfloat16(x);
    return __builtin_bit_cast(ushort, h);
}

// ---------------- embed + pos + LN0: 32 rows/block, 8 rows/wave ----------------
__global__ __launch_bounds__(256)
void embed_ln3(const float* __restrict__ x, const float* __restrict__ Wemb,
               const float* __restrict__ bemb, const float* __restrict__ pos,
               const float* __restrict__ g0, const float* __restrict__ b0,
               float* __restrict__ H)
{
    __shared__ float xs[32][40];
    const int t = threadIdx.x, w = t >> 6, l = t & 63;
    const long row0 = (long)blockIdx.x * 32;          // 32 rows/block (2048%32==0)
    // stage x for 32 rows (5 KB, coalesced)
    for (int idx = t; idx < 32 * 40; idx += 256)
        ((float*)xs)[idx] = x[row0 * 40 + idx];
    __syncthreads();

    const int r0 = w * 8;                             // wave handles rows r0..r0+7
    const int nbase = (int)((row0 + r0) & 2047);
    const float4 be = *(const float4*)&bemb[l * 4];
    float4 acc[8];
    #pragma unroll 8
    for (int j = 0; j < 8; ++j) {
        const float4 pv = *(const float4*)&pos[(long)(nbase + j) * 256 + l * 4];
        acc[j].x = be.x + pv.x; acc[j].y = be.y + pv.y;
        acc[j].z = be.z + pv.z; acc[j].w = be.w + pv.w;
    }
    for (int f = 0; f < 40; ++f) {
        const float4 wv = *(const float4*)&Wemb[f * 256 + l * 4];
        #pragma unroll 8
        for (int j = 0; j < 8; ++j) {
            const float xf = xs[r0 + j][f];
            acc[j].x += xf * wv.x; acc[j].y += xf * wv.y;
            acc[j].z += xf * wv.z; acc[j].w += xf * wv.w;
        }
    }
    const float4 gv = *(const float4*)&g0[l * 4];
    const float4 bv = *(const float4*)&b0[l * 4];
    #pragma unroll 8
    for (int j = 0; j < 8; ++j) {
        float s = acc[j].x + acc[j].y + acc[j].z + acc[j].w;
        #pragma unroll
        for (int m = 32; m >= 1; m >>= 1) s += __shfl_xor(s, m);
        const float mean = s * (1.0f / 256.0f);
        const float dx = acc[j].x - mean, dy = acc[j].y - mean;
        const float dz = acc[j].z - mean, dw = acc[j].w - mean;
        float q = dx * dx + dy * dy + dz * dz + dw * dw;
        #pragma unroll
        for (int m = 32; m >= 1; m >>= 1) q += __shfl_xor(q, m);
        const float inv = rsqrtf(q * (1.0f / 256.0f) + 1e-5f);
        float4 y;
        y.x = dx * inv * gv.x + bv.x;
        y.y = dy * inv * gv.y + bv.y;
        y.z = dz * inv * gv.z + bv.z;
        y.w = dw * inv * gv.w + bv.w;
        *(float4*)&H[(row0 + r0 + j) * 256 + l * 4] = y;
    }
}

// ---------------- LayerNorm fp32 -> bf16 ----------------
__global__ __launch_bounds__(256)
void ln_kernel(const float* __restrict__ X, const float* __restrict__ g,
               const float* __restrict__ b, ushort* __restrict__ Y)
{
    const int row = blockIdx.x * 4 + (threadIdx.x >> 6);
    const int lane = threadIdx.x & 63;
    const long base = (long)row * 256 + lane * 4;
    float4 xv = *(const float4*)&X[base];
    float s = xv.x + xv.y + xv.z + xv.w;
    #pragma unroll
    for (int m = 32; m >= 1; m >>= 1) s += __shfl_xor(s, m);
    const float mean = s * (1.0f / 256.0f);
    const float dx = xv.x - mean, dy = xv.y - mean, dz = xv.z - mean, dw = xv.w - mean;
    float q = dx * dx + dy * dy + dz * dz + dw * dw;
    #pragma unroll
    for (int m = 32; m >= 1; m >>= 1) q += __shfl_xor(q, m);
    const float inv = rsqrtf(q * (1.0f / 256.0f) + 1e-5f);
    const float4 gv = *(const float4*)&g[lane * 4];
    const float4 bv = *(const float4*)&b[lane * 4];
    ushort4 y;
    y.x = f2bf(dx * inv * gv.x + bv.x);
    y.y = f2bf(dy * inv * gv.y + bv.y);
    y.z = f2bf(dz * inv * gv.z + bv.z);
    y.w = f2bf(dw * inv * gv.w + bv.w);
    *(ushort4*)&Y[base] = y;
}

// ---------------- weight transpose + cast ----------------
__global__ __launch_bounds__(256)
void transpose_cast(const float* __restrict__ in, ushort* __restrict__ out,
                    int R, int C, long sIn, long sOut)
{
    __shared__ float tile[32][33];
    in += (long)blockIdx.z * sIn; out += (long)blockIdx.z * sOut;
    const int c0 = blockIdx.x * 32, r0 = blockIdx.y * 32;
    const int tx = threadIdx.x & 31, ty = threadIdx.x >> 5;
    #pragma unroll
    for (int j = 0; j < 4; ++j)
        tile[ty + j * 8][tx] = in[(long)(r0 + ty + j * 8) * C + c0 + tx];
    __syncthreads();
    #pragma unroll
    for (int j = 0; j < 4; ++j)
        out[(long)(c0 + ty + j * 8) * R + r0 + tx] = f2bf(tile[tx][ty + j * 8]);
}

// ---------------- activation transpose: abf [32768,256] -> aT [16][256][2048] ----------------
__global__ __launch_bounds__(256)
void transpose_act(const ushort* __restrict__ in, ushort* __restrict__ out)
{
    __shared__ ushort tile[32][33];
    const int c0 = blockIdx.x * 32, r0 = blockIdx.y * 32;
    const int tx = threadIdx.x & 31, ty = threadIdx.x >> 5;
    #pragma unroll
    for (int j = 0; j < 4; ++j)
        tile[ty + j * 8][tx] = in[(long)(r0 + ty + j * 8) * 256 + c0 + tx];
    __syncthreads();
    const int b = r0 >> 11, nn = r0 & 2047;
    #pragma unroll
    for (int j = 0; j < 4; ++j)
        out[((long)(b * 256 + c0 + ty + j * 8)) * 2048 + nn + tx] = tile[tx][ty + j * 8];
}

// ---------------- bf16 MFMA GEMM, 64x64x32 tile, single-buffer 8KB LDS ----------------
template<int OBF16, int ACT, int HASB, int ACCF>
__global__ __launch_bounds__(256)
void gemm64(const ushort* __restrict__ A, const ushort* __restrict__ BT,
            const float* __restrict__ bias, void* __restrict__ Cout,
            int Kd, int lda, int ldb, int ldc,
            long sA, long sBT, long sC)
{
    __shared__ ushort Als[64 * 32];
    __shared__ ushort Bls[64 * 32];
    const int bz = blockIdx.z;
    const ushort* Ab = A + (long)bz * sA;
    const ushort* Bb = BT + (long)bz * sBT;
    const int m0 = blockIdx.x * 64, n0 = blockIdx.y * 64;
    const int t = threadIdx.x, l = t & 63, w = t >> 6;
    const int wr = w >> 1, wc = w & 1;
    const int fr = l & 15, fq = l >> 4;

    f32x4 acc[2][2];
    #pragma unroll
    for (int m = 0; m < 2; ++m)
        #pragma unroll
        for (int n = 0; n < 2; ++n) acc[m][n] = f32x4{0.f, 0.f, 0.f, 0.f};

    const int srow = t >> 2;
    const int skcol = (t & 3) * 8;
    const int dst0 = w * 512;
    const ushort* Abase = Ab + (long)(m0 + srow) * lda + skcol;
    const ushort* Bbase = Bb + (long)(n0 + srow) * ldb + skcol;

    for (int kk = 0; kk < Kd; kk += 32) {
        __builtin_amdgcn_global_load_lds((const GLOBAL_AS void*)(Abase + kk),
                                         (LDS_AS void*)&Als[dst0], 16, 0, 0);
        __builtin_amdgcn_global_load_lds((const GLOBAL_AS void*)(Bbase + kk),
                                         (LDS_AS void*)&Bls[dst0], 16, 0, 0);
        __syncthreads();
        bf16x8 af[2], bfv[2];
        #pragma unroll
        for (int m = 0; m < 2; ++m)
            af[m] = *(const bf16x8*)&Als[(wr * 32 + m * 16 + fr) * 32 + fq * 8];
        #pragma unroll
        for (int n = 0; n < 2; ++n)
            bfv[n] = *(const bf16x8*)&Bls[(wc * 32 + n * 16 + fr) * 32 + fq * 8];
        #pragma unroll
        for (int m = 0; m < 2; ++m)
            #pragma unroll
            for (int n = 0; n < 2; ++n)
                acc[m][n] = __builtin_amdgcn_mfma_f32_16x16x32_bf16(af[m], bfv[n], acc[m][n], 0, 0, 0);
        __syncthreads();
    }

    float bsv[2];
    #pragma unroll
    for (int n = 0; n < 2; ++n) bsv[n] = HASB ? bias[n0 + wc * 32 + n * 16 + fr] : 0.f;
    #pragma unroll
    for (int m = 0; m < 2; ++m) {
        #pragma unroll
        for (int r = 0; r < 4; ++r) {
            const int grow = m0 + wr * 32 + m * 16 + fq * 4 + r;
            const long rowoff = (long)grow * ldc + n0 + wc * 32 + fr;
            #pragma unroll
            for (int n = 0; n < 2; ++n) {
                float v = acc[m][n][r] + bsv[n];
                if (ACT) v = gelu_f(v);
                const long off = rowoff + n * 16;
                if (OBF16) {
                    ((ushort*)Cout)[(long)bz * sC + off] = f2bf(v);
                } else {
                    float* Cp = (float*)Cout + (long)bz * sC;
                    if (ACCF) v += Cp[off];
                    Cp[off] = v;
                }
            }
        }
    }
}

// ---------------- fused MFMA attention, swapped-operand, P in registers ----------------
__global__ __launch_bounds__(256)
void attn_mfma2(const ushort* __restrict__ Q, const ushort* __restrict__ Kp,
                const ushort* __restrict__ VpT, ushort* __restrict__ O)
{
    __shared__ ushort Kls[256 * 40];   // 20.5 KB
    __shared__ ushort Vls[32 * 264];   // 16.9 KB
    const int qt = blockIdx.x, h = blockIdx.y, b = blockIdx.z;
    const int n0 = qt * 64;
    const int t = threadIdx.x, w = t >> 6, l = t & 63;
    const int fr = l & 15, fq = l >> 4;

    #pragma unroll
    for (int it = 0; it < 4; ++it) {
        const int r = (t >> 2) + it * 64, c = (t & 3) * 8;
        *(float4*)&Kls[r * 40 + c] =
            *(const float4*)&Kp[((long)(b * 256 + r)) * 256 + h * 32 + c];
    }
    {
        const int r = t >> 3, c0 = (t & 7) * 32;
        const ushort* src = VpT + ((long)(b * 256 + h * 32 + r)) * 256 + c0;
        #pragma unroll
        for (int j = 0; j < 4; ++j)
            *(float4*)&Vls[r * 264 + c0 + j * 8] = *(const float4*)(src + j * 8);
    }
    const bf16x8 bq = *(const bf16x8*)
        &Q[((long)(b * 2048 + n0 + w * 16 + fr)) * 256 + h * 32 + fq * 8];
    __syncthreads();

    f32x4 s[16];
    #pragma unroll
    for (int n = 0; n < 16; ++n) {
        const bf16x8 ak = *(const bf16x8*)&Kls[(n * 16 + fr) * 40 + fq * 8];
        s[n] = __builtin_amdgcn_mfma_f32_16x16x32_bf16(ak, bq, f32x4{0.f,0.f,0.f,0.f}, 0, 0, 0);
    }
    const float scale = 0.17677669529663687f;
    float mx = -1e30f;
    #pragma unroll
    for (int n = 0; n < 16; ++n)
        #pragma unroll
        for (int r = 0; r < 4; ++r) { s[n][r] *= scale; mx = fmaxf(mx, s[n][r]); }
    mx = fmaxf(mx, __shfl_xor(mx, 16));
    mx = fmaxf(mx, __shfl_xor(mx, 32));
    float sm = 0.f;
    unsigned int p[16][2];
    #pragma unroll
    for (int n = 0; n < 16; ++n) {
        float e0 = __expf(s[n][0] - mx), e1 = __expf(s[n][1] - mx);
        float e2 = __expf(s[n][2] - mx), e3 = __expf(s[n][3] - mx);
        sm += (e0 + e1) + (e2 + e3);
        p[n][0] = ((unsigned int)f2bf(e1) << 16) | f2bf(e0);
        p[n][1] = ((unsigned int)f2bf(e3) << 16) | f2bf(e2);
    }
    sm += __shfl_xor(sm, 16);
    sm += __shfl_xor(sm, 32);

    const int fqa = fq & 1, fqb = fq >> 1;
    f32x4 o[2] = {f32x4{0.f,0.f,0.f,0.f}, f32x4{0.f,0.f,0.f,0.f}};
    #pragma unroll
    for (int kk = 0; kk < 8; ++kk) {
        u32x4 bw;
        #pragma unroll
        for (int wd = 0; wd < 4; ++wd) {
            const int srcl = fr + ((2 * fqa + (wd >> 1)) << 4);
            const unsigned int v0 = __shfl((int)p[2 * kk][wd & 1], srcl);
            const unsigned int v1 = __shfl((int)p[2 * kk + 1][wd & 1], srcl);
            bw[wd] = fqb ? v1 : v0;
        }
        const bf16x8 breg = __builtin_bit_cast(bf16x8, bw);
        #pragma unroll
        for (int nd = 0; nd < 2; ++nd) {
            const bf16x8 av = *(const bf16x8*)&Vls[(nd * 16 + fr) * 264 + kk * 32 + fq * 8];
            o[nd] = __builtin_amdgcn_mfma_f32_16x16x32_bf16(av, breg, o[nd], 0, 0, 0);
        }
    }
    const float inv = 1.0f / sm;
    const long rowbase = ((long)(b * 2048 + n0 + w * 16 + fr)) * 256 + h * 32;
    #pragma unroll
    for (int nd = 0; nd < 2; ++nd) {
        ushort4 y;
        y.x = f2bf(o[nd][0] * inv); y.y = f2bf(o[nd][1] * inv);
        y.z = f2bf(o[nd][2] * inv); y.w = f2bf(o[nd][3] * inv);
        *(ushort4*)&O[rowbase + nd * 16 + fq * 4] = y;
    }
}

// ---------------- final head ----------------
__global__ __launch_bounds__(256)
void out_kernel(const float* __restrict__ H, const float* __restrict__ Wout,
                const float* __restrict__ bout, float* __restrict__ out)
{
    const int row = blockIdx.x * 4 + (threadIdx.x >> 6);
    const int lane = threadIdx.x & 63;
    float4 hv = *(const float4*)&H[(long)row * 256 + lane * 4];
    float4 wv = *(const float4*)&Wout[lane * 4];
    float s = hv.x * wv.x + hv.y * wv.y + hv.z * wv.z + hv.w * wv.w;
    #pragma unroll
    for (int m = 32; m >= 1; m >>= 1) s += __shfl_xor(s, m);
    if (lane == 0) out[row] = s + bout[0];
}

extern "C" void kernel_launch(void* const* d_in, const int* in_sizes, int n_in,
                              void* d_out, int out_size, void* d_ws, size_t ws_size,
                              hipStream_t stream)
{
    const float* x    = (const float*)d_in[0];
    const float* Wemb = (const float*)d_in[1];
    const float* bemb = (const float*)d_in[2];
    const float* pos  = (const float*)d_in[3];
    const float* ln0g = (const float*)d_in[4];
    const float* ln0b = (const float*)d_in[5];
    const float* ln1g = (const float*)d_in[6];
    const float* ln1b = (const float*)d_in[7];
    const float* Wq   = (const float*)d_in[8];
    const float* Wk   = (const float*)d_in[9];
    const float* Wv   = (const float*)d_in[10];
    const float* Ek   = (const float*)d_in[11];
    const float* Ev   = (const float*)d_in[12];
    const float* Wo   = (const float*)d_in[13];
    const float* bo   = (const float*)d_in[14];
    const float* ln2g = (const float*)d_in[15];
    const float* ln2b = (const float*)d_in[16];
    const float* W1   = (const float*)d_in[17];
    const float* b1   = (const float*)d_in[18];
    const float* W2   = (const float*)d_in[19];
    const float* b2   = (const float*)d_in[20];
    const float* Wout = (const float*)d_in[21];
    const float* bout = (const float*)d_in[22];

    char* ws = (char*)d_ws;
    float*  h    = (float*)(ws + 0);
    ushort* abf  = (ushort*)(ws + 33554432L);
    ushort* aT   = (ushort*)(ws + 50331648L);
    ushort* kp   = (ushort*)(ws + 67108864L);
    ushort* vpT  = (ushort*)(ws + 69206016L);
    ushort* apkv = (ushort*)(ws + 71303168L);
    ushort* qbf  = (ushort*)(ws + 100663296L);
    ushort* hid  = (ushort*)(ws + 50331648L);
    ushort* WT   = (ushort*)(ws + 117440512L);
    ushort* WqT  = WT;
    ushort* WkT  = WT + 262144;
    ushort* WvT  = WT + 524288;
    ushort* WoT  = WT + 786432;
    ushort* W1T  = WT + 1048576;
    ushort* W2T  = WT + 2097152;
    ushort* EkvT = WT + 3145728;
    float* outp = (float*)d_out;

    transpose_cast<<<dim3(8, 8, 4), 256, 0, stream>>>(Wq, WqT, 256, 256, 65536, 65536);
    transpose_cast<<<dim3(8, 8, 4), 256, 0, stream>>>(Wk, WkT, 256, 256, 65536, 65536);
    transpose_cast<<<dim3(8, 8, 4), 256, 0, stream>>>(Wv, WvT, 256, 256, 65536, 65536);
    transpose_cast<<<dim3(8, 8, 4), 256, 0, stream>>>(Wo, WoT, 256, 256, 65536, 65536);
    transpose_cast<<<dim3(32, 8, 4), 256, 0, stream>>>(W1, W1T, 256, 1024, 262144, 262144);
    transpose_cast<<<dim3(8, 32, 4), 256, 0, stream>>>(W2, W2T, 1024, 256, 262144, 262144);
    transpose_cast<<<dim3(8, 64, 4), 256, 0, stream>>>(Ek, EkvT, 2048, 256, 524288, 1048576);
    transpose_cast<<<dim3(8, 64, 4), 256, 0, stream>>>(Ev, EkvT + 524288, 2048, 256, 524288, 1048576);

    embed_ln3<<<1024, 256, 0, stream>>>(x, Wemb, bemb, pos, ln0g, ln0b, h);
    ln_kernel<<<8192, 256, 0, stream>>>(h, ln1g, ln1b, abf);
    transpose_act<<<dim3(8, 1024), 256, 0, stream>>>(abf, aT);

    for (int i = 0; i < 4; ++i) {
        const ushort* WqT_i = WqT + i * 65536;
        const ushort* WkT_i = WkT + i * 65536;
        const ushort* WvT_i = WvT + i * 65536;
        const ushort* WoT_i = WoT + i * 65536;
        const ushort* W1T_i = W1T + i * 262144;
        const ushort* W2T_i = W2T + i * 262144;
        const ushort* EkvT_i = EkvT + (long)i * 1048576;

        // q = a @ Wq (bf16) — 2048 blocks
        gemm64<1,0,0,0><<<dim3(512, 4, 1), 256, 0, stream>>>(abf, WqT_i, nullptr, qbf,
            256, 256, 256, 256, 0, 0, 0);
        // apkv[b] = [Ek^T; Ev^T] @ a[b] (bf16)
        gemm64<1,0,0,0><<<dim3(8, 4, 16), 256, 0, stream>>>(EkvT_i, aT, nullptr, apkv,
            2048, 2048, 2048, 256, 0, 524288, 131072);
        // kp[b] = apk[b] @ Wk (bf16, row=key)
        gemm64<1,0,0,0><<<dim3(4, 4, 16), 256, 0, stream>>>(apkv, WkT_i, nullptr, kp,
            256, 256, 256, 256, 131072, 0, 65536);
        // vpT[b] = Wv^T @ apv[b]^T (bf16, row=d, col=key)
        gemm64<1,0,0,0><<<dim3(4, 4, 16), 256, 0, stream>>>(WvT_i, apkv + 65536, nullptr, vpT,
            256, 256, 256, 256, 0, 131072, 65536);
        // fused MFMA attention -> abf (bf16)
        attn_mfma2<<<dim3(32, 8, 16), 256, 0, stream>>>(qbf, kp, vpT, abf);
        // h += attnout @ Wo + bo (f32 RMW epilogue)
        gemm64<0,0,1,1><<<dim3(512, 4, 1), 256, 0, stream>>>(abf, WoT_i, bo + i * 256, h,
            256, 256, 256, 256, 0, 0, 0);
        // abf = LN2(h)
        ln_kernel<<<8192, 256, 0, stream>>>(h, ln2g + i * 256, ln2b + i * 256, abf);
        // hid = gelu(a @ W1 + b1) (bf16) — 8192 blocks
        gemm64<1,1,1,0><<<dim3(512, 16, 1), 256, 0, stream>>>(abf, W1T_i,
            b1 + (long)i * 1024, hid, 256, 256, 256, 1024, 0, 0, 0);
        // h += hid @ W2 + b2 (f32 RMW epilogue)
        gemm64<0,0,1,1><<<dim3(512, 4, 1), 256, 0, stream>>>(hid, W2T_i, b2 + i * 256, h,
            1024, 1024, 1024, 256, 0, 0, 0);
        if (i < 3) {
            ln_kernel<<<8192, 256, 0, stream>>>(h, ln1g + (i + 1) * 256,
                ln1b + (i + 1) * 256, abf);
            transpose_act<<<dim3(8, 1024), 256, 0, stream>>>(abf, aT);
        }
    }
    out_kernel<<<8192, 256, 0, stream>>>(h, Wout, bout, outp);
}